// Round 12
// baseline (497.793 us; speedup 1.0000x reference)
//
#include <hip/hip_runtime.h>

#define NN 50000
#define NE 800000
#define ET 850000   // NE + NN self-loops
#define NBLK 196    // ceil(NN/256) for the parallel scan; also radix buckets
#define NAGG1 3125  // k_agg1 grid (= NN/16), also rows of `part`
#define MEGA_W    448                   // weight-prep blocks (114688/256)
#define MEGA_HIST 3125                  // hist blocks (NE/256)
#define MEGA_GRID (MEGA_W + MEGA_HIST)
#define GM64 782                        // (NN+63)/64
#define GM128 391                       // (NN+127)/128
#define SCAT 3321                       // ceil(ET/256): radix pass blocks

typedef unsigned short ushort_t;
typedef unsigned int uint_t;
typedef __attribute__((ext_vector_type(8))) short short8;
typedef __attribute__((ext_vector_type(4))) float f32x4;

// ---------------------------------------------------------------- utilities
__device__ __forceinline__ float elu1(float x) {
    return x > 0.f ? x : (__expf(x) - 1.f);
}
__device__ __forceinline__ float bf2f(ushort_t u) {
    return __uint_as_float(((uint_t)u) << 16);
}
__device__ __forceinline__ ushort_t f2bf(float f) {   // round-to-nearest-even
    uint_t u = __float_as_uint(f);
    u += 0x7FFFu + ((u >> 16) & 1u);
    return (ushort_t)(u >> 16);
}
__device__ __forceinline__ uint_t pack2(float a, float b) {
    return (uint_t)f2bf(a) | ((uint_t)f2bf(b) << 16);
}
__device__ __forceinline__ void gl_lds16(const ushort_t* g, ushort_t* l) {
    // async global->LDS, 16B/lane; LDS dest = wave-uniform base + lane*16
    __builtin_amdgcn_global_load_lds((const __attribute__((address_space(1))) void*)g,
                                     (__attribute__((address_space(3))) void*)l,
                                     16, 0, 0);
}
// bf16 pair (packed in a dword) -> two fp32, exact (bf16 = truncated fp32)
#define ACC2(q, w) do { \
    a0 += (w) * __uint_as_float((q).x << 16); \
    a1 += (w) * __uint_as_float((q).x & 0xFFFF0000u); \
    a2 += (w) * __uint_as_float((q).y << 16); \
    a3 += (w) * __uint_as_float((q).y & 0xFFFF0000u); } while (0)

// ---------------------------------------------------------------- mega prep
// blocks [0,448): weight split-transposes with column permutation (frag nt
//   slot l16 = global col l16*4+nt -> lanes own 4 consecutive output cols).
// blocks [448,3573): dst-degree histogram (cursor pre-zeroed by memset;
//   the +1 self-loop is folded into k_scan1).
__global__ void k_mega(const float* __restrict__ w_in, const float* __restrict__ W0,
                       const float* __restrict__ W1, const float* __restrict__ W2,
                       ushort_t* __restrict__ wiT, ushort_t* __restrict__ w0T,
                       ushort_t* __restrict__ w1T, ushort_t* __restrict__ w2T,
                       const int* __restrict__ dst, int* __restrict__ cursor,
                       float* __restrict__ gsum) {
    int b = blockIdx.x, t = threadIdx.x;
    if (b < MEGA_W) {
        if (b == 0 && t < 64) gsum[t] = 0.f;
        int i = b * 256 + t;                      // 0..114687
        const float* W; ushort_t* Bt; int K, N, j;
        if (i < 16384)       { W = w_in; Bt = wiT; K = 256; N = 64;  j = i; }
        else if (i < 32768)  { W = W0;   Bt = w0T; K = 64;  N = 256; j = i - 16384; }
        else if (i < 98304)  { W = W1;   Bt = w1T; K = 256; N = 256; j = i - 32768; }
        else                 { W = W2;   Bt = w2T; K = 256; N = 64;  j = i - 98304; }
        int k = j / N, n = j % N;
        int jj = n & 63;
        int rp = (n & ~63) | ((jj & 3) << 4) | (jj >> 2);   // permuted row
        float v = W[j];
        ushort_t h = f2bf(v);
        Bt[(size_t)rp * 2 * K + k] = h;
        Bt[(size_t)rp * 2 * K + K + k] = f2bf(v - bf2f(h));
    } else {
        int e = (b - MEGA_W) * 256 + t;
        if (e < NE) atomicAdd(&cursor[dst[e]], 1);
    }
}

// ---------------------------------------------------------------- scan
// exclusive scan of (cnt[i]+1) -> row_ptr (the +1 is the self-loop)
__global__ void k_scan1(const int* __restrict__ cnt, int* __restrict__ excl,
                        int* __restrict__ bsum) {
    __shared__ int wsum[4];
    int t = threadIdx.x, lane = t & 63, w = t >> 6;
    int i = blockIdx.x * 256 + t;
    int v = (i < NN) ? cnt[i] + 1 : 0;
    int x = v;
    #pragma unroll
    for (int o = 1; o < 64; o <<= 1) {
        int y = __shfl_up(x, o, 64);
        if (lane >= o) x += y;
    }
    if (lane == 63) wsum[w] = x;
    __syncthreads();
    int wo = 0;
    #pragma unroll
    for (int k = 0; k < 4; k++) wo += (k < w) ? wsum[k] : 0;
    if (i < NN) excl[i] = x - v + wo;
    if (t == 255) bsum[blockIdx.x] = wo + x;     // block total
}

__global__ void k_scan2(int* __restrict__ bsum) {   // 1 block, 256 threads
    __shared__ int wsum[4];
    int t = threadIdx.x, lane = t & 63, w = t >> 6;
    int v = (t < NBLK) ? bsum[t] : 0;
    int x = v;
    #pragma unroll
    for (int o = 1; o < 64; o <<= 1) {
        int y = __shfl_up(x, o, 64);
        if (lane >= o) x += y;
    }
    if (lane == 63) wsum[w] = x;
    __syncthreads();
    int wo = 0;
    #pragma unroll
    for (int k = 0; k < 4; k++) wo += (k < w) ? wsum[k] : 0;
    if (t < NBLK) bsum[t] = x - v + wo;          // exclusive
}

// also initializes radix bucket cursors: bucket b = nodes [b*256,(b+1)*256),
// bcur[b*16] = row_ptr[b*256] (t==0 of each of the 196 blocks).
__global__ void k_scan3(int* __restrict__ row_ptr, const int* __restrict__ bsum,
                        int* __restrict__ cursor, int* __restrict__ bcur) {
    int i = blockIdx.x * 256 + threadIdx.x;
    if (i < NN) {
        int r = row_ptr[i] + bsum[blockIdx.x];
        row_ptr[i] = r;
        cursor[i] = r;
        if (threadIdx.x == 0) bcur[blockIdx.x * 16] = r;   // 64B-padded bucket cursor
    }
    if (i == 0) row_ptr[NN] = ET;
}

// ---------------------------------------------------------------- GEMM body
// C[M x N](bf16) = A[M x K] @ (Bh + Bl), split-bf16 weights.
// AF32: A is fp32; staging converts RNE in-register + ds_write_b128 (bit-
// identical to a separate cast pass). Else A is bf16 via global_load_lds.
// BM=64*MT, BN=16*NT (NT=8 for N=256 GEMMs -> halves A refetch). 256 thr.
// Weight cols permuted (see k_mega) -> ushort4 C stores, float4 bias loads.
template<bool ELU, bool BIAS, bool EDOT, int MT, int NT, bool AF32>
__device__ __forceinline__ void gemm_body(const void* __restrict__ Av,
                                          const ushort_t* __restrict__ Bt,
                                          const float* __restrict__ bias,
                                          ushort_t* __restrict__ C,
                                          const float* __restrict__ a_s,
                                          const float* __restrict__ a_d,
                                          float* __restrict__ es,
                                          float* __restrict__ ed,
                                          int esStride, int M, int K, int N,
                                          int bx, int by) {
    constexpr int HG = NT / 4;                    // 64-col groups per block
    constexpr int BOFF = MT * 4096;               // ushort offset of B region
    __shared__ __align__(16) ushort_t lds[MT * 4096 + NT * 2048];
    int tid = threadIdx.x;
    int wave = tid >> 6, lane = tid & 63;
    int quad = lane >> 4, l16 = lane & 15;
    int mb = bx * (64 * MT), nb = by * (16 * NT);
    int K2 = 2 * K;

    f32x4 acc[MT][NT];
    #pragma unroll
    for (int mt = 0; mt < MT; mt++)
        #pragma unroll
        for (int nt = 0; nt < NT; nt++)
            acc[mt][nt] = (f32x4){0.f, 0.f, 0.f, 0.f};

    for (int k0 = 0; k0 < K; k0 += 64) {
        // ---- stage B first (async DMA) ----
        #pragma unroll
        for (int c = 0; c < NT; c++) {
            int id = wave * NT + c;               // 0 .. 4*NT-1
            int ntile = id % NT;
            int ks = (id / NT) & 1;
            int split = id / (2 * NT);
            int n = nb + ntile * 16 + l16;
            int col = split * K + k0 + ks * 32 + quad * 8;
            gl_lds16(Bt + (size_t)n * K2 + col,
                     &lds[BOFF + ((split * NT + ntile) * 2 + ks) * 512]);
        }
        // ---- stage A ----
        #pragma unroll
        for (int c = 0; c < 2 * MT; c++) {
            int mt = (MT == 2) ? (wave * 2 + (c >> 1)) : wave;
            int ks = (MT == 2) ? (c & 1) : c;
            int row = mb + mt * 16 + l16;
            row = min(row, M - 1);
            int col = k0 + ks * 32 + quad * 8;
            if constexpr (AF32) {
                const float* Af = (const float*)Av;
                float4 v0 = *(const float4*)(Af + (size_t)row * K + col);
                float4 v1 = *(const float4*)(Af + (size_t)row * K + col + 4);
                uint4 pk;
                pk.x = pack2(v0.x, v0.y); pk.y = pack2(v0.z, v0.w);
                pk.z = pack2(v1.x, v1.y); pk.w = pack2(v1.z, v1.w);
                *(uint4*)&lds[(mt * 2 + ks) * 512 + lane * 8] = pk;
            } else {
                gl_lds16((const ushort_t*)Av + (size_t)row * K + col,
                         &lds[(mt * 2 + ks) * 512]);
            }
        }
        __syncthreads();
        #pragma unroll
        for (int ks = 0; ks < 2; ks++) {
            short8 af[MT];
            #pragma unroll
            for (int mt = 0; mt < MT; mt++)
                af[mt] = *(const short8*)&lds[((wave * MT + mt) * 2 + ks) * 512 + lane * 8];
            #pragma unroll
            for (int split = 0; split < 2; split++) {
                short8 bf[NT];
                #pragma unroll
                for (int nt = 0; nt < NT; nt++)
                    bf[nt] = *(const short8*)&lds[BOFF + ((split * NT + nt) * 2 + ks) * 512 + lane * 8];
                #pragma unroll
                for (int mt = 0; mt < MT; mt++)
                    #pragma unroll
                    for (int nt = 0; nt < NT; nt++)
                        acc[mt][nt] = __builtin_amdgcn_mfma_f32_16x16x32_bf16(
                            af[mt], bf[nt], acc[mt][nt], 0, 0, 0);
            }
        }
        __syncthreads();
    }
    // ---- epilogue: frag nt slot l16 = global col l16*4 + (nt%4), group nt/4 ----
    float4 as4[HG], ad4[HG], b4[HG];
    #pragma unroll
    for (int hg = 0; hg < HG; hg++) {
        int cbase = nb + hg * 64 + l16 * 4;
        if (EDOT) {
            as4[hg] = *(const float4*)(a_s + (size_t)(by * HG + hg) * 64 + l16 * 4);
            ad4[hg] = *(const float4*)(a_d + (size_t)(by * HG + hg) * 64 + l16 * 4);
        }
        if (BIAS) b4[hg] = *(const float4*)(bias + cbase);
    }
    #pragma unroll
    for (int mt = 0; mt < MT; mt++) {
        int mrow = mb + (wave * MT + mt) * 16 + quad * 4;
        #pragma unroll
        for (int r = 0; r < 4; r++) {
            int m = mrow + r;
            bool mv = m < M;
            #pragma unroll
            for (int hg = 0; hg < HG; hg++) {
                float v0 = acc[mt][hg * 4 + 0][r];
                float v1 = acc[mt][hg * 4 + 1][r];
                float v2 = acc[mt][hg * 4 + 2][r];
                float v3 = acc[mt][hg * 4 + 3][r];
                if constexpr (EDOT) {
                    float ps = v0 * as4[hg].x + v1 * as4[hg].y + v2 * as4[hg].z + v3 * as4[hg].w;
                    float pd = v0 * ad4[hg].x + v1 * ad4[hg].y + v2 * ad4[hg].z + v3 * ad4[hg].w;
                    #pragma unroll
                    for (int o = 8; o >= 1; o >>= 1) {
                        ps += __shfl_xor(ps, o, 64);
                        pd += __shfl_xor(pd, o, 64);
                    }
                    if (l16 == 0 && mv) {
                        int head = by * HG + hg;
                        es[(size_t)m * esStride + head] = ps;
                        ed[(size_t)m * esStride + head] = pd;
                    }
                }
                if (mv) {
                    if (BIAS) { v0 += b4[hg].x; v1 += b4[hg].y; v2 += b4[hg].z; v3 += b4[hg].w; }
                    if (ELU) { v0 = elu1(v0); v1 = elu1(v1); v2 = elu1(v2); v3 = elu1(v3); }
                    ushort4 o;
                    o.x = f2bf(v0); o.y = f2bf(v1); o.z = f2bf(v2); o.w = f2bf(v3);
                    *(ushort4*)&C[(size_t)m * N + nb + hg * 64 + l16 * 4] = o;
                }
            }
        }
    }
}

template<bool ELU, bool BIAS, bool EDOT, int MT, int NT>
__global__ __launch_bounds__(256) void gemm_mfma(const ushort_t* __restrict__ A,
                                                 const ushort_t* __restrict__ Bt,
                                                 const float* __restrict__ bias,
                                                 ushort_t* __restrict__ C,
                                                 const float* __restrict__ a_s,
                                                 const float* __restrict__ a_d,
                                                 float* __restrict__ es,
                                                 float* __restrict__ ed,
                                                 int esStride, int M, int K, int N) {
    gemm_body<ELU, BIAS, EDOT, MT, NT, false>(A, Bt, bias, C, a_s, a_d, es, ed,
                                              esStride, M, K, N, blockIdx.x, blockIdx.y);
}

// ---- fused launch A: input-projection GEMM reading fp32 x directly
//      (blocks [0,GM64)) + radix PASS 1: partition edges by dst>>8 into
//      tmp (pairs), bucket cursors advance monotonically -> write-combined
//      stores into 196 hot regions (R9: flat scatter had 16x write amp).
__global__ __launch_bounds__(256) void k_fuseA(const float* __restrict__ x,
                                               const ushort_t* __restrict__ Bt,
                                               const float* __restrict__ bias,
                                               ushort_t* __restrict__ C,
                                               const int* __restrict__ ei,
                                               int* __restrict__ bcur,
                                               int2* __restrict__ tmp) {
    if (blockIdx.x < GM64) {
        gemm_body<true, true, false, 1, 4, true>(x, Bt, bias, C, nullptr, nullptr,
                                                 nullptr, nullptr, 0, NN, 256, 64,
                                                 blockIdx.x, 0);
    } else {
        int e = (blockIdx.x - GM64) * 256 + threadIdx.x;
        if (e >= ET) return;
        int s, d;
        if (e < NE) { s = ei[e]; d = ei[NE + e]; }
        else        { s = d = e - NE; }
        int pos = atomicAdd(&bcur[(d >> 8) * 16], 1);
        tmp[pos] = make_int2(s, d);
    }
}

// ---- fused launch B: GAT-layer-0 GEMM (flattened 391x2 grid, blocks
//      [0,782)) + radix PASS 2: tmp is bucket-grouped, so consecutive
//      entries write within one bucket's ~17KB csr window (L2-resident).
__global__ __launch_bounds__(256) void k_fuseB(const ushort_t* __restrict__ A,
                                               const ushort_t* __restrict__ Bt,
                                               ushort_t* __restrict__ C,
                                               const float* __restrict__ a_s,
                                               const float* __restrict__ a_d,
                                               float* __restrict__ es,
                                               float* __restrict__ ed,
                                               const int2* __restrict__ tmp,
                                               int* __restrict__ cursor,
                                               int* __restrict__ csr) {
    if (blockIdx.x < 2 * GM128) {
        int g = blockIdx.x;
        gemm_body<false, false, true, 2, 8, false>(A, Bt, nullptr, C, a_s, a_d, es, ed,
                                                   4, NN, 64, 256, g % GM128, g / GM128);
    } else {
        int e = (blockIdx.x - 2 * GM128) * 256 + threadIdx.x;
        if (e >= ET) return;
        int2 p = tmp[e];
        int pos = atomicAdd(&cursor[p.y], 1);
        csr[pos] = p.x;
    }
}

// ------------------------------------------------- softmax aggregate, 4 heads
// 1 wave per node; fast path deg<=64; gather unrolled x4 (R7: x8 regressed via
// VGPR 24->36). Near fabric floor: 207 MB FETCH @ ~3.6 TB/s observed ceiling.
template<bool BFOUT>
__global__ __launch_bounds__(256) void k_agg4(const ushort_t* __restrict__ xl,
                                              const float* __restrict__ es,
                                              const float* __restrict__ ed,
                                              const int* __restrict__ row_ptr,
                                              const int* __restrict__ csr,
                                              const float* __restrict__ bias,
                                              void* __restrict__ outv) {
    __shared__ float wlds[4][256];
    int lane = threadIdx.x & 63, wave = threadIdx.x >> 6;
    int node = blockIdx.x * 4 + wave;
    if (node >= NN) return;
    int head = lane >> 4;
    int start = row_ptr[node], end = row_ptr[node + 1];
    int deg = end - start;
    float4 edv = *(const float4*)(ed + (size_t)node * 4);
    float edh[4] = {edv.x, edv.y, edv.z, edv.w};
    float a0 = 0.f, a1 = 0.f, a2 = 0.f, a3 = 0.f;
    const uint_t* xb = (const uint_t*)xl;

    if (deg <= 64) {
        int i = start + lane;
        bool valid = i < end;
        int idx = csr[valid ? i : start];
        float4 ev = *(const float4*)(es + (size_t)idx * 4);
        float e[4] = {ev.x, ev.y, ev.z, ev.w};
        #pragma unroll
        for (int h = 0; h < 4; h++) {
            float v = e[h] + edh[h];
            v = v > 0.f ? v : 0.2f * v;
            e[h] = valid ? v : -1e30f;
        }
        float cm[4];
        #pragma unroll
        for (int h = 0; h < 4; h++) cm[h] = e[h];
        #pragma unroll
        for (int o = 32; o >= 1; o >>= 1)
            #pragma unroll
            for (int h = 0; h < 4; h++) cm[h] = fmaxf(cm[h], __shfl_xor(cm[h], o, 64));
        float cs[4];
        #pragma unroll
        for (int h = 0; h < 4; h++) cs[h] = valid ? __expf(e[h] - cm[h]) : 0.f;
        #pragma unroll
        for (int o = 32; o >= 1; o >>= 1)
            #pragma unroll
            for (int h = 0; h < 4; h++) cs[h] += __shfl_xor(cs[h], o, 64);
        float4 wv;
        wv.x = valid ? __expf(e[0] - cm[0]) / cs[0] : 0.f;
        wv.y = valid ? __expf(e[1] - cm[1]) / cs[1] : 0.f;
        wv.z = valid ? __expf(e[2] - cm[2]) / cs[2] : 0.f;
        wv.w = valid ? __expf(e[3] - cm[3]) / cs[3] : 0.f;
        *(float4*)&wlds[wave][lane * 4] = wv;
        int t = 0;
        for (; t + 4 <= deg; t += 4) {
            int s0 = __shfl(idx, t + 0, 64), s1 = __shfl(idx, t + 1, 64);
            int s2 = __shfl(idx, t + 2, 64), s3 = __shfl(idx, t + 3, 64);
            uint2 q0 = *(const uint2*)(xb + (size_t)s0 * 128 + lane * 2);
            uint2 q1 = *(const uint2*)(xb + (size_t)s1 * 128 + lane * 2);
            uint2 q2 = *(const uint2*)(xb + (size_t)s2 * 128 + lane * 2);
            uint2 q3 = *(const uint2*)(xb + (size_t)s3 * 128 + lane * 2);
            float w0 = wlds[wave][(t + 0) * 4 + head], w1 = wlds[wave][(t + 1) * 4 + head];
            float w2 = wlds[wave][(t + 2) * 4 + head], w3 = wlds[wave][(t + 3) * 4 + head];
            ACC2(q0, w0); ACC2(q1, w1); ACC2(q2, w2); ACC2(q3, w3);
        }
        for (; t < deg; ++t) {
            int s0 = __shfl(idx, t, 64);
            uint2 q0 = *(const uint2*)(xb + (size_t)s0 * 128 + lane * 2);
            float w0 = wlds[wave][t * 4 + head];
            ACC2(q0, w0);
        }
    } else {
        float m[4], ssum[4];
        #pragma unroll
        for (int h = 0; h < 4; h++) { m[h] = -1e30f; ssum[h] = 0.f; }
        for (int base = start; base < end; base += 64) {
            int i = base + lane;
            bool valid = i < end;
            int idx = csr[valid ? i : start];
            float4 ev = *(const float4*)(es + (size_t)idx * 4);
            float e[4] = {ev.x, ev.y, ev.z, ev.w};
            #pragma unroll
            for (int h = 0; h < 4; h++) {
                float v = e[h] + edh[h];
                v = v > 0.f ? v : 0.2f * v;
                e[h] = valid ? v : -1e30f;
            }
            float cm[4];
            #pragma unroll
            for (int h = 0; h < 4; h++) cm[h] = e[h];
            #pragma unroll
            for (int o = 32; o >= 1; o >>= 1)
                #pragma unroll
                for (int h = 0; h < 4; h++) cm[h] = fmaxf(cm[h], __shfl_xor(cm[h], o, 64));
            float cs[4];
            #pragma unroll
            for (int h = 0; h < 4; h++) cs[h] = valid ? __expf(e[h] - cm[h]) : 0.f;
            #pragma unroll
            for (int o = 32; o >= 1; o >>= 1)
                #pragma unroll
                for (int h = 0; h < 4; h++) cs[h] += __shfl_xor(cs[h], o, 64);
            #pragma unroll
            for (int h = 0; h < 4; h++) {
                float mn = fmaxf(m[h], cm[h]);
                ssum[h] = ssum[h] * __expf(m[h] - mn) + cs[h] * __expf(cm[h] - mn);
                m[h] = mn;
            }
        }
        float inv[4];
        #pragma unroll
        for (int h = 0; h < 4; h++) inv[h] = 1.f / ssum[h];
        for (int base = start; base < end; base += 64) {
            int i = base + lane;
            bool valid = i < end;
            int idx = csr[valid ? i : start];
            int cnt = min(64, end - base);
            float4 ev = *(const float4*)(es + (size_t)idx * 4);
            float e[4] = {ev.x, ev.y, ev.z, ev.w};
            #pragma unroll
            for (int h = 0; h < 4; h++) {
                float v = e[h] + edh[h];
                v = v > 0.f ? v : 0.2f * v;
                e[h] = valid ? __expf(v - m[h]) * inv[h] : 0.f;
            }
            float4 wv; wv.x = e[0]; wv.y = e[1]; wv.z = e[2]; wv.w = e[3];
            *(float4*)&wlds[wave][lane * 4] = wv;
            for (int t = 0; t < cnt; ++t) {
                int s = __shfl(idx, t, 64);
                float w = wlds[wave][t * 4 + head];
                uint2 q = *(const uint2*)(xb + (size_t)s * 128 + lane * 2);
                ACC2(q, w);
            }
        }
    }

    float o0 = elu1(a0 + bias[lane * 4 + 0]);
    float o1 = elu1(a1 + bias[lane * 4 + 1]);
    float o2 = elu1(a2 + bias[lane * 4 + 2]);
    float o3 = elu1(a3 + bias[lane * 4 + 3]);
    if constexpr (BFOUT) {
        ushort4 o; o.x = f2bf(o0); o.y = f2bf(o1); o.z = f2bf(o2); o.w = f2bf(o3);
        *(ushort4*)((ushort_t*)outv + (size_t)node * 256 + lane * 4) = o;
    } else {
        float4 o; o.x = o0; o.y = o1; o.z = o2; o.w = o3;
        *(float4*)((float*)outv + (size_t)node * 256 + lane * 4) = o;
    }
}

// ------------------------------------------------- softmax aggregate, 1 head
// 4 nodes per wave (16-lane groups); partial mean-pool stored per block
// (no atomics — R4: 200k same-line atomics serialized at the coherent point).
__global__ __launch_bounds__(256) void k_agg1(const ushort_t* __restrict__ xl,
                                              const float* __restrict__ es,
                                              const float* __restrict__ ed,
                                              const int* __restrict__ row_ptr,
                                              const int* __restrict__ csr,
                                              const float* __restrict__ bias,
                                              float* __restrict__ part) {
    __shared__ float wlds[4][64];
    __shared__ float ps[4][64];
    int lane = threadIdx.x & 63, wave = threadIdx.x >> 6;
    int g = lane >> 4, l16 = lane & 15;
    int node = blockIdx.x * 16 + wave * 4 + g;
    bool vn = node < NN;
    int start = vn ? row_ptr[node] : 0;
    int end   = vn ? row_ptr[node + 1] : 0;
    float edl = vn ? ed[node] : 0.f;

    float m = -1e30f, ssum = 0.f;
    for (int base = start; base < end; base += 16) {
        int i = base + l16;
        bool valid = i < end;
        int idx = csr[valid ? i : start];
        float e = es[idx] + edl;
        e = e > 0.f ? e : 0.2f * e;
        e = valid ? e : -1e30f;
        float cm = e;
        #pragma unroll
        for (int o = 8; o >= 1; o >>= 1) cm = fmaxf(cm, __shfl_xor(cm, o, 64));
        float cs = valid ? __expf(e - cm) : 0.f;
        #pragma unroll
        for (int o = 8; o >= 1; o >>= 1) cs += __shfl_xor(cs, o, 64);
        float mn = fmaxf(m, cm);
        ssum = ssum * __expf(m - mn) + cs * __expf(cm - mn);
        m = mn;
    }
    float inv = 1.f / ssum;

    float a0 = 0.f, a1 = 0.f, a2 = 0.f, a3 = 0.f;
    const uint_t* xb = (const uint_t*)xl;
    for (int base = start; base < end; base += 16) {
        int i = base + l16;
        bool valid = i < end;
        int idx = csr[valid ? i : start];
        int cnt = min(16, end - base);
        float e = es[idx] + edl;
        e = e > 0.f ? e : 0.2f * e;
        wlds[wave][g * 16 + l16] = valid ? __expf(e - m) * inv : 0.f;
        int t = 0;
        for (; t + 4 <= cnt; t += 4) {
            int s0 = __shfl(idx, g * 16 + t + 0, 64), s1 = __shfl(idx, g * 16 + t + 1, 64);
            int s2 = __shfl(idx, g * 16 + t + 2, 64), s3 = __shfl(idx, g * 16 + t + 3, 64);
            uint2 q0 = *(const uint2*)(xb + (size_t)s0 * 32 + l16 * 2);
            uint2 q1 = *(const uint2*)(xb + (size_t)s1 * 32 + l16 * 2);
            uint2 q2 = *(const uint2*)(xb + (size_t)s2 * 32 + l16 * 2);
            uint2 q3 = *(const uint2*)(xb + (size_t)s3 * 32 + l16 * 2);
            float w0 = wlds[wave][g * 16 + t + 0], w1 = wlds[wave][g * 16 + t + 1];
            float w2 = wlds[wave][g * 16 + t + 2], w3 = wlds[wave][g * 16 + t + 3];
            ACC2(q0, w0); ACC2(q1, w1); ACC2(q2, w2); ACC2(q3, w3);
        }
        for (; t < cnt; ++t) {
            int s = __shfl(idx, g * 16 + t, 64);
            float w = wlds[wave][g * 16 + t];
            uint2 q = *(const uint2*)(xb + (size_t)s * 32 + l16 * 2);
            ACC2(q, w);
        }
    }

    float o[4];
    o[0] = vn ? elu1(a0 + bias[l16 * 4 + 0]) : 0.f;
    o[1] = vn ? elu1(a1 + bias[l16 * 4 + 1]) : 0.f;
    o[2] = vn ? elu1(a2 + bias[l16 * 4 + 2]) : 0.f;
    o[3] = vn ? elu1(a3 + bias[l16 * 4 + 3]) : 0.f;
    #pragma unroll
    for (int j = 0; j < 4; j++) {
        o[j] += __shfl_xor(o[j], 16, 64);
        o[j] += __shfl_xor(o[j], 32, 64);
    }
    if (lane < 16) {
        float4 v; v.x = o[0]; v.y = o[1]; v.z = o[2]; v.w = o[3];
        *(float4*)&ps[wave][l16 * 4] = v;
    }
    __syncthreads();
    int tid = threadIdx.x;
    if (tid < 64) {
        float tot = ps[0][tid] + ps[1][tid] + ps[2][tid] + ps[3][tid];
        part[(size_t)blockIdx.x * 64 + tid] = tot;
    }
}

// ---- reduce part[NAGG1][64] -> gsum[64] (few blocks => few atomics) ----
__global__ void k_red(const float* __restrict__ part, float* __restrict__ gsum) {
    __shared__ float sm[4][64];
    int t = threadIdx.x, c = t & 63, w = t >> 6;
    float s = 0.f;
    for (int r = blockIdx.x * 4 + w; r < NAGG1; r += gridDim.x * 4)
        s += part[(size_t)r * 64 + c];
    sm[w][c] = s;
    __syncthreads();
    if (w == 0) {
        float tot = sm[0][c] + sm[1][c] + sm[2][c] + sm[3][c];
        atomicAdd(&gsum[c], tot);
    }
}

// ---------------------------------------------------------------- final
__global__ void k_final(const float* __restrict__ gsum, const float* __restrict__ w_out,
                        const float* __restrict__ b_out, float* __restrict__ out) {
    int j = threadIdx.x;   // 128
    float s = b_out[j];
    const float invn = 1.f / (float)NN;
    #pragma unroll 8
    for (int k = 0; k < 64; k++)
        s += (gsum[k] * invn) * w_out[k * 128 + j];
    out[j] = s;
}

// ---------------------------------------------------------------- launcher
extern "C" void kernel_launch(void* const* d_in, const int* in_sizes, int n_in,
                              void* d_out, int out_size, void* d_ws, size_t ws_size,
                              hipStream_t stream) {
    const float* x    = (const float*)d_in[0];
    const int*   ei   = (const int*)d_in[1];
    const float* w_in = (const float*)d_in[2];
    const float* b_in = (const float*)d_in[3];
    const float* W0   = (const float*)d_in[4];
    const float* as0  = (const float*)d_in[5];
    const float* ad0  = (const float*)d_in[6];
    const float* bb0  = (const float*)d_in[7];
    const float* W1   = (const float*)d_in[8];
    const float* as1  = (const float*)d_in[9];
    const float* ad1  = (const float*)d_in[10];
    const float* bb1  = (const float*)d_in[11];
    const float* W2   = (const float*)d_in[12];
    const float* as2  = (const float*)d_in[13];
    const float* ad2  = (const float*)d_in[14];
    const float* bb2  = (const float*)d_in[15];
    const float* w_out= (const float*)d_in[16];
    const float* b_out= (const float*)d_in[17];
    float* out = (float*)d_out;

    char* p = (char*)d_ws;
    size_t off = 0;
    auto take = [&](size_t bytes) {
        char* r = p + off;
        off = (off + bytes + 255) & ~(size_t)255;
        return r;
    };
    ushort_t* h0b    = (ushort_t*)take((size_t)NN * 64 * 2);  //  6.4 MB
    ushort_t* xl_bf  = (ushort_t*)take((size_t)NN * 256 * 2); // 25.6 MB
    ushort_t* hb_bf  = (ushort_t*)take((size_t)NN * 256 * 2); // 25.6 MB
    ushort_t* h2_bf  = (ushort_t*)take((size_t)NN * 64 * 2);  //  6.4 MB
    ushort_t* wiT    = (ushort_t*)take((size_t)64 * 512 * 2);
    ushort_t* w0T    = (ushort_t*)take((size_t)256 * 128 * 2);
    ushort_t* w1T    = (ushort_t*)take((size_t)256 * 512 * 2);
    ushort_t* w2T    = (ushort_t*)take((size_t)64 * 512 * 2);
    float*    es     = (float*)take((size_t)NN * 4 * 4);
    float*    ed     = (float*)take((size_t)NN * 4 * 4);
    int*      row_ptr= (int*)take((size_t)(NN + 1) * 4);
    int*      cursor = (int*)take((size_t)NN * 4);
    int*      csr    = (int*)take((size_t)ET * 4);
    int2*     tmp    = (int2*)take((size_t)ET * 8);           //  6.8 MB
    int*      bcur   = (int*)take((size_t)NBLK * 16 * 4);     //  64B/bucket
    int*      bsum   = (int*)take((size_t)NBLK * 4);
    float*    part   = (float*)take((size_t)NAGG1 * 64 * 4);  // 0.8 MB
    float*    gsum   = (float*)take(64 * 4);

    // cursor := 0 (degree histogram base; self-loop +1 folded into scan1)
    hipMemsetAsync(cursor, 0, (size_t)NN * 4, stream);

    // ---- mega prep: weight split-transpose + dst histogram ----
    k_mega<<<MEGA_GRID, 256, 0, stream>>>(w_in, W0, W1, W2, wiT, w0T, w1T, w2T,
                                          ei + NE, cursor, gsum);

    // ---- scan (cnt+1) -> row_ptr; scan3 also seeds bucket cursors ----
    k_scan1<<<NBLK, 256, 0, stream>>>(cursor, row_ptr, bsum);
    k_scan2<<<1, 256, 0, stream>>>(bsum);
    k_scan3<<<NBLK, 256, 0, stream>>>(row_ptr, bsum, cursor, bcur);

    // ---- fused A: input projection GEMM (fp32 A) || radix pass 1 ----
    k_fuseA<<<GM64 + SCAT, 256, 0, stream>>>(x, wiT, b_in, h0b, ei, bcur, tmp);

    // ---- fused B: GAT layer-0 GEMM (es/ed epilogue) || radix pass 2 ----
    k_fuseB<<<2 * GM128 + SCAT, 256, 0, stream>>>(h0b, w0T, xl_bf, as0, ad0,
                                                  es, ed, tmp, cursor, csr);
    k_agg4<true><<<(NN + 3) / 4, 256, 0, stream>>>(xl_bf, es, ed, row_ptr, csr, bb0, hb_bf);

    // ---- GAT layer 1 (heads=4, concat); BN=128 ----
    gemm_mfma<false, false, true, 2, 8><<<dim3(GM128, 2), 256, 0, stream>>>(
        hb_bf, w1T, nullptr, xl_bf, as1, ad1, es, ed, 4, NN, 256, 256);
    k_agg4<true><<<(NN + 3) / 4, 256, 0, stream>>>(xl_bf, es, ed, row_ptr, csr, bb1, hb_bf);

    // ---- GAT layer 2 (heads=1) + partial mean-pool ----
    gemm_mfma<false, false, true, 1, 4><<<dim3(GM64, 1), 256, 0, stream>>>(
        hb_bf, w2T, nullptr, h2_bf, as2, ad2, es, ed, 1, NN, 256, 64);
    k_agg1<<<NAGG1, 256, 0, stream>>>(h2_bf, es, ed, row_ptr, csr, bb2, part);
    k_red <<<64, 256, 0, stream>>>(part, gsum);

    // ---- output projection ----
    k_final<<<1, 128, 0, stream>>>(gsum, w_out, b_out, out);
}

// Round 13
// 445.844 us; speedup vs baseline: 1.1165x; 1.1165x over previous
//
#include <hip/hip_runtime.h>

#define NN 50000
#define NE 800000
#define ET 850000   // NE + NN self-loops
#define NBLK 196    // ceil(NN/256) for the parallel scan
#define NAGG1 3125  // k_agg1 grid (= NN/16), also rows of `part`
#define MEGA_W    448                   // weight-prep blocks (114688/256)
#define MEGA_HIST 3125                  // hist blocks (NE/256)
#define MEGA_GRID (MEGA_W + MEGA_HIST)
#define GM64 782                        // (NN+63)/64
#define GM128 391                       // (NN+127)/128
#define EHALF 425000                    // scatter split point
#define SCA 1661                        // ceil(EHALF/256)
#define SCB 1661                        // ceil((ET-EHALF)/256)

typedef unsigned short ushort_t;
typedef unsigned int uint_t;
typedef __attribute__((ext_vector_type(8))) short short8;
typedef __attribute__((ext_vector_type(4))) float f32x4;

// ---------------------------------------------------------------- utilities
__device__ __forceinline__ float elu1(float x) {
    return x > 0.f ? x : (__expf(x) - 1.f);
}
__device__ __forceinline__ float bf2f(ushort_t u) {
    return __uint_as_float(((uint_t)u) << 16);
}
__device__ __forceinline__ ushort_t f2bf(float f) {   // round-to-nearest-even
    uint_t u = __float_as_uint(f);
    u += 0x7FFFu + ((u >> 16) & 1u);
    return (ushort_t)(u >> 16);
}
__device__ __forceinline__ uint_t pack2(float a, float b) {
    return (uint_t)f2bf(a) | ((uint_t)f2bf(b) << 16);
}
__device__ __forceinline__ void gl_lds16(const ushort_t* g, ushort_t* l) {
    // async global->LDS, 16B/lane; LDS dest = wave-uniform base + lane*16
    __builtin_amdgcn_global_load_lds((const __attribute__((address_space(1))) void*)g,
                                     (__attribute__((address_space(3))) void*)l,
                                     16, 0, 0);
}
// bf16 pair (packed in a dword) -> two fp32, exact (bf16 = truncated fp32)
#define ACC2(q, w) do { \
    a0 += (w) * __uint_as_float((q).x << 16); \
    a1 += (w) * __uint_as_float((q).x & 0xFFFF0000u); \
    a2 += (w) * __uint_as_float((q).y << 16); \
    a3 += (w) * __uint_as_float((q).y & 0xFFFF0000u); } while (0)

// ---------------------------------------------------------------- mega prep
// blocks [0,448): weight split-transposes with column permutation:
//   within each 64-col group, col j -> row (j&3)*16 + (j>>2): GEMM frag nt
//   slot l16 = global col l16*4+nt -> lanes own 4 consecutive output cols.
//   (x is NOT pre-cast — fuseA's GEMM converts fp32 A in-register; R11.)
// blocks [448,3573): dst-degree histogram (cursor pre-zeroed by memset;
//   the +1 self-loop is folded into k_scan1).
// NOTE R12: radix-bucketed scatter REGRESSED (443->498): bucket cursors
//   shared across concurrent waves interleave partial-line writes (same 16x
//   write amp) + 850k atomics on only 196 lines serialize. Flat scatter
//   hidden under GEMMs (this version) is the best known.
__global__ void k_mega(const float* __restrict__ w_in, const float* __restrict__ W0,
                       const float* __restrict__ W1, const float* __restrict__ W2,
                       ushort_t* __restrict__ wiT, ushort_t* __restrict__ w0T,
                       ushort_t* __restrict__ w1T, ushort_t* __restrict__ w2T,
                       const int* __restrict__ dst, int* __restrict__ cursor,
                       float* __restrict__ gsum) {
    int b = blockIdx.x, t = threadIdx.x;
    if (b < MEGA_W) {
        if (b == 0 && t < 64) gsum[t] = 0.f;
        int i = b * 256 + t;                      // 0..114687
        const float* W; ushort_t* Bt; int K, N, j;
        if (i < 16384)       { W = w_in; Bt = wiT; K = 256; N = 64;  j = i; }
        else if (i < 32768)  { W = W0;   Bt = w0T; K = 64;  N = 256; j = i - 16384; }
        else if (i < 98304)  { W = W1;   Bt = w1T; K = 256; N = 256; j = i - 32768; }
        else                 { W = W2;   Bt = w2T; K = 256; N = 64;  j = i - 98304; }
        int k = j / N, n = j % N;
        int jj = n & 63;
        int rp = (n & ~63) | ((jj & 3) << 4) | (jj >> 2);   // permuted row
        float v = W[j];
        ushort_t h = f2bf(v);
        Bt[(size_t)rp * 2 * K + k] = h;
        Bt[(size_t)rp * 2 * K + K + k] = f2bf(v - bf2f(h));
    } else {
        int e = (b - MEGA_W) * 256 + t;
        if (e < NE) atomicAdd(&cursor[dst[e]], 1);
    }
}

// ---------------------------------------------------------------- scan
// exclusive scan of (cnt[i]+1) -> row_ptr (the +1 is the self-loop)
__global__ void k_scan1(const int* __restrict__ cnt, int* __restrict__ excl,
                        int* __restrict__ bsum) {
    __shared__ int wsum[4];
    int t = threadIdx.x, lane = t & 63, w = t >> 6;
    int i = blockIdx.x * 256 + t;
    int v = (i < NN) ? cnt[i] + 1 : 0;
    int x = v;
    #pragma unroll
    for (int o = 1; o < 64; o <<= 1) {
        int y = __shfl_up(x, o, 64);
        if (lane >= o) x += y;
    }
    if (lane == 63) wsum[w] = x;
    __syncthreads();
    int wo = 0;
    #pragma unroll
    for (int k = 0; k < 4; k++) wo += (k < w) ? wsum[k] : 0;
    if (i < NN) excl[i] = x - v + wo;
    if (t == 255) bsum[blockIdx.x] = wo + x;     // block total
}

__global__ void k_scan2(int* __restrict__ bsum) {   // 1 block, 256 threads
    __shared__ int wsum[4];
    int t = threadIdx.x, lane = t & 63, w = t >> 6;
    int v = (t < NBLK) ? bsum[t] : 0;
    int x = v;
    #pragma unroll
    for (int o = 1; o < 64; o <<= 1) {
        int y = __shfl_up(x, o, 64);
        if (lane >= o) x += y;
    }
    if (lane == 63) wsum[w] = x;
    __syncthreads();
    int wo = 0;
    #pragma unroll
    for (int k = 0; k < 4; k++) wo += (k < w) ? wsum[k] : 0;
    if (t < NBLK) bsum[t] = x - v + wo;          // exclusive
}

__global__ void k_scan3(int* __restrict__ row_ptr, const int* __restrict__ bsum,
                        int* __restrict__ cursor) {
    int i = blockIdx.x * 256 + threadIdx.x;
    if (i < NN) {
        int r = row_ptr[i] + bsum[blockIdx.x];
        row_ptr[i] = r;
        cursor[i] = r;
    }
    if (i == 0) row_ptr[NN] = ET;
}

// ---------------------------------------------------------------- GEMM body
// C[M x N](bf16) = A[M x K] @ (Bh + Bl), split-bf16 weights.
// AF32: A is fp32; staging converts RNE in-register + ds_write_b128 (bit-
// identical to a separate cast pass). Else A is bf16 via global_load_lds.
// BM=64*MT, BN=16*NT (NT=8 for N=256 GEMMs -> halves A refetch). 256 thr.
// Weight cols permuted (see k_mega) -> ushort4 C stores, float4 bias loads.
template<bool ELU, bool BIAS, bool EDOT, int MT, int NT, bool AF32>
__device__ __forceinline__ void gemm_body(const void* __restrict__ Av,
                                          const ushort_t* __restrict__ Bt,
                                          const float* __restrict__ bias,
                                          ushort_t* __restrict__ C,
                                          const float* __restrict__ a_s,
                                          const float* __restrict__ a_d,
                                          float* __restrict__ es,
                                          float* __restrict__ ed,
                                          int esStride, int M, int K, int N,
                                          int bx, int by) {
    constexpr int HG = NT / 4;                    // 64-col groups per block
    constexpr int BOFF = MT * 4096;               // ushort offset of B region
    __shared__ __align__(16) ushort_t lds[MT * 4096 + NT * 2048];
    int tid = threadIdx.x;
    int wave = tid >> 6, lane = tid & 63;
    int quad = lane >> 4, l16 = lane & 15;
    int mb = bx * (64 * MT), nb = by * (16 * NT);
    int K2 = 2 * K;

    f32x4 acc[MT][NT];
    #pragma unroll
    for (int mt = 0; mt < MT; mt++)
        #pragma unroll
        for (int nt = 0; nt < NT; nt++)
            acc[mt][nt] = (f32x4){0.f, 0.f, 0.f, 0.f};

    for (int k0 = 0; k0 < K; k0 += 64) {
        // ---- stage B first (async DMA) ----
        #pragma unroll
        for (int c = 0; c < NT; c++) {
            int id = wave * NT + c;               // 0 .. 4*NT-1
            int ntile = id % NT;
            int ks = (id / NT) & 1;
            int split = id / (2 * NT);
            int n = nb + ntile * 16 + l16;
            int col = split * K + k0 + ks * 32 + quad * 8;
            gl_lds16(Bt + (size_t)n * K2 + col,
                     &lds[BOFF + ((split * NT + ntile) * 2 + ks) * 512]);
        }
        // ---- stage A ----
        #pragma unroll
        for (int c = 0; c < 2 * MT; c++) {
            int mt = (MT == 2) ? (wave * 2 + (c >> 1)) : wave;
            int ks = (MT == 2) ? (c & 1) : c;
            int row = mb + mt * 16 + l16;
            row = min(row, M - 1);
            int col = k0 + ks * 32 + quad * 8;
            if constexpr (AF32) {
                const float* Af = (const float*)Av;
                float4 v0 = *(const float4*)(Af + (size_t)row * K + col);
                float4 v1 = *(const float4*)(Af + (size_t)row * K + col + 4);
                uint4 pk;
                pk.x = pack2(v0.x, v0.y); pk.y = pack2(v0.z, v0.w);
                pk.z = pack2(v1.x, v1.y); pk.w = pack2(v1.z, v1.w);
                *(uint4*)&lds[(mt * 2 + ks) * 512 + lane * 8] = pk;
            } else {
                gl_lds16((const ushort_t*)Av + (size_t)row * K + col,
                         &lds[(mt * 2 + ks) * 512]);
            }
        }
        __syncthreads();
        #pragma unroll
        for (int ks = 0; ks < 2; ks++) {
            short8 af[MT];
            #pragma unroll
            for (int mt = 0; mt < MT; mt++)
                af[mt] = *(const short8*)&lds[((wave * MT + mt) * 2 + ks) * 512 + lane * 8];
            #pragma unroll
            for (int split = 0; split < 2; split++) {
                short8 bf[NT];
                #pragma unroll
                for (int nt = 0; nt < NT; nt++)
                    bf[nt] = *(const short8*)&lds[BOFF + ((split * NT + nt) * 2 + ks) * 512 + lane * 8];
                #pragma unroll
                for (int mt = 0; mt < MT; mt++)
                    #pragma unroll
                    for (int nt = 0; nt < NT; nt++)
                        acc[mt][nt] = __builtin_amdgcn_mfma_f32_16x16x32_bf16(
                            af[mt], bf[nt], acc[mt][nt], 0, 0, 0);
            }
        }
        __syncthreads();
    }
    // ---- epilogue: frag nt slot l16 = global col l16*4 + (nt%4), group nt/4 ----
    float4 as4[HG], ad4[HG], b4[HG];
    #pragma unroll
    for (int hg = 0; hg < HG; hg++) {
        int cbase = nb + hg * 64 + l16 * 4;
        if (EDOT) {
            as4[hg] = *(const float4*)(a_s + (size_t)(by * HG + hg) * 64 + l16 * 4);
            ad4[hg] = *(const float4*)(a_d + (size_t)(by * HG + hg) * 64 + l16 * 4);
        }
        if (BIAS) b4[hg] = *(const float4*)(bias + cbase);
    }
    #pragma unroll
    for (int mt = 0; mt < MT; mt++) {
        int mrow = mb + (wave * MT + mt) * 16 + quad * 4;
        #pragma unroll
        for (int r = 0; r < 4; r++) {
            int m = mrow + r;
            bool mv = m < M;
            #pragma unroll
            for (int hg = 0; hg < HG; hg++) {
                float v0 = acc[mt][hg * 4 + 0][r];
                float v1 = acc[mt][hg * 4 + 1][r];
                float v2 = acc[mt][hg * 4 + 2][r];
                float v3 = acc[mt][hg * 4 + 3][r];
                if constexpr (EDOT) {
                    float ps = v0 * as4[hg].x + v1 * as4[hg].y + v2 * as4[hg].z + v3 * as4[hg].w;
                    float pd = v0 * ad4[hg].x + v1 * ad4[hg].y + v2 * ad4[hg].z + v3 * ad4[hg].w;
                    #pragma unroll
                    for (int o = 8; o >= 1; o >>= 1) {
                        ps += __shfl_xor(ps, o, 64);
                        pd += __shfl_xor(pd, o, 64);
                    }
                    if (l16 == 0 && mv) {
                        int head = by * HG + hg;
                        es[(size_t)m * esStride + head] = ps;
                        ed[(size_t)m * esStride + head] = pd;
                    }
                }
                if (mv) {
                    if (BIAS) { v0 += b4[hg].x; v1 += b4[hg].y; v2 += b4[hg].z; v3 += b4[hg].w; }
                    if (ELU) { v0 = elu1(v0); v1 = elu1(v1); v2 = elu1(v2); v3 = elu1(v3); }
                    ushort4 o;
                    o.x = f2bf(v0); o.y = f2bf(v1); o.z = f2bf(v2); o.w = f2bf(v3);
                    *(ushort4*)&C[(size_t)m * N + nb + hg * 64 + l16 * 4] = o;
                }
            }
        }
    }
}

template<bool ELU, bool BIAS, bool EDOT, int MT, int NT>
__global__ __launch_bounds__(256) void gemm_mfma(const ushort_t* __restrict__ A,
                                                 const ushort_t* __restrict__ Bt,
                                                 const float* __restrict__ bias,
                                                 ushort_t* __restrict__ C,
                                                 const float* __restrict__ a_s,
                                                 const float* __restrict__ a_d,
                                                 float* __restrict__ es,
                                                 float* __restrict__ ed,
                                                 int esStride, int M, int K, int N) {
    gemm_body<ELU, BIAS, EDOT, MT, NT, false>(A, Bt, bias, C, a_s, a_d, es, ed,
                                              esStride, M, K, N, blockIdx.x, blockIdx.y);
}

// ---- fused launch A: input-projection GEMM reading fp32 x directly
//      (blocks [0,GM64)) + CSR scatter of edges [0,EHALF).
__global__ __launch_bounds__(256) void k_fuseA(const float* __restrict__ x,
                                               const ushort_t* __restrict__ Bt,
                                               const float* __restrict__ bias,
                                               ushort_t* __restrict__ C,
                                               const int* __restrict__ ei,
                                               int* __restrict__ cursor,
                                               int* __restrict__ csr) {
    if (blockIdx.x < GM64) {
        gemm_body<true, true, false, 1, 4, true>(x, Bt, bias, C, nullptr, nullptr,
                                                 nullptr, nullptr, 0, NN, 256, 64,
                                                 blockIdx.x, 0);
    } else {
        int e = (blockIdx.x - GM64) * 256 + threadIdx.x;
        if (e >= EHALF) return;               // EHALF < NE: all real edges
        int s = ei[e], d = ei[NE + e];
        int pos = atomicAdd(&cursor[d], 1);
        csr[pos] = s;
    }
}

// ---- fused launch B: GAT-layer-0 GEMM (flattened 391x2 grid, blocks
//      [0,782)) + CSR scatter of edges [EHALF,ET) incl. self-loops.
__global__ __launch_bounds__(256) void k_fuseB(const ushort_t* __restrict__ A,
                                               const ushort_t* __restrict__ Bt,
                                               ushort_t* __restrict__ C,
                                               const float* __restrict__ a_s,
                                               const float* __restrict__ a_d,
                                               float* __restrict__ es,
                                               float* __restrict__ ed,
                                               const int* __restrict__ ei,
                                               int* __restrict__ cursor,
                                               int* __restrict__ csr) {
    if (blockIdx.x < 2 * GM128) {
        int g = blockIdx.x;
        gemm_body<false, false, true, 2, 8, false>(A, Bt, nullptr, C, a_s, a_d, es, ed,
                                                   4, NN, 64, 256, g % GM128, g / GM128);
    } else {
        int e = EHALF + (blockIdx.x - 2 * GM128) * 256 + threadIdx.x;
        if (e >= ET) return;
        int s, d;
        if (e < NE) { s = ei[e]; d = ei[NE + e]; }
        else        { s = d = e - NE; }
        int pos = atomicAdd(&cursor[d], 1);
        csr[pos] = s;
    }
}

// ------------------------------------------------- softmax aggregate, 4 heads
// 1 wave per node; fast path deg<=64; gather unrolled x4 (R7: x8 regressed via
// VGPR 24->36). Near fabric floor: 207 MB FETCH @ ~3.6 TB/s observed ceiling.
template<bool BFOUT>
__global__ __launch_bounds__(256) void k_agg4(const ushort_t* __restrict__ xl,
                                              const float* __restrict__ es,
                                              const float* __restrict__ ed,
                                              const int* __restrict__ row_ptr,
                                              const int* __restrict__ csr,
                                              const float* __restrict__ bias,
                                              void* __restrict__ outv) {
    __shared__ float wlds[4][256];
    int lane = threadIdx.x & 63, wave = threadIdx.x >> 6;
    int node = blockIdx.x * 4 + wave;
    if (node >= NN) return;
    int head = lane >> 4;
    int start = row_ptr[node], end = row_ptr[node + 1];
    int deg = end - start;
    float4 edv = *(const float4*)(ed + (size_t)node * 4);
    float edh[4] = {edv.x, edv.y, edv.z, edv.w};
    float a0 = 0.f, a1 = 0.f, a2 = 0.f, a3 = 0.f;
    const uint_t* xb = (const uint_t*)xl;

    if (deg <= 64) {
        int i = start + lane;
        bool valid = i < end;
        int idx = csr[valid ? i : start];
        float4 ev = *(const float4*)(es + (size_t)idx * 4);
        float e[4] = {ev.x, ev.y, ev.z, ev.w};
        #pragma unroll
        for (int h = 0; h < 4; h++) {
            float v = e[h] + edh[h];
            v = v > 0.f ? v : 0.2f * v;
            e[h] = valid ? v : -1e30f;
        }
        float cm[4];
        #pragma unroll
        for (int h = 0; h < 4; h++) cm[h] = e[h];
        #pragma unroll
        for (int o = 32; o >= 1; o >>= 1)
            #pragma unroll
            for (int h = 0; h < 4; h++) cm[h] = fmaxf(cm[h], __shfl_xor(cm[h], o, 64));
        float cs[4];
        #pragma unroll
        for (int h = 0; h < 4; h++) cs[h] = valid ? __expf(e[h] - cm[h]) : 0.f;
        #pragma unroll
        for (int o = 32; o >= 1; o >>= 1)
            #pragma unroll
            for (int h = 0; h < 4; h++) cs[h] += __shfl_xor(cs[h], o, 64);
        float4 wv;
        wv.x = valid ? __expf(e[0] - cm[0]) / cs[0] : 0.f;
        wv.y = valid ? __expf(e[1] - cm[1]) / cs[1] : 0.f;
        wv.z = valid ? __expf(e[2] - cm[2]) / cs[2] : 0.f;
        wv.w = valid ? __expf(e[3] - cm[3]) / cs[3] : 0.f;
        *(float4*)&wlds[wave][lane * 4] = wv;
        int t = 0;
        for (; t + 4 <= deg; t += 4) {
            int s0 = __shfl(idx, t + 0, 64), s1 = __shfl(idx, t + 1, 64);
            int s2 = __shfl(idx, t + 2, 64), s3 = __shfl(idx, t + 3, 64);
            uint2 q0 = *(const uint2*)(xb + (size_t)s0 * 128 + lane * 2);
            uint2 q1 = *(const uint2*)(xb + (size_t)s1 * 128 + lane * 2);
            uint2 q2 = *(const uint2*)(xb + (size_t)s2 * 128 + lane * 2);
            uint2 q3 = *(const uint2*)(xb + (size_t)s3 * 128 + lane * 2);
            float w0 = wlds[wave][(t + 0) * 4 + head], w1 = wlds[wave][(t + 1) * 4 + head];
            float w2 = wlds[wave][(t + 2) * 4 + head], w3 = wlds[wave][(t + 3) * 4 + head];
            ACC2(q0, w0); ACC2(q1, w1); ACC2(q2, w2); ACC2(q3, w3);
        }
        for (; t < deg; ++t) {
            int s0 = __shfl(idx, t, 64);
            uint2 q0 = *(const uint2*)(xb + (size_t)s0 * 128 + lane * 2);
            float w0 = wlds[wave][t * 4 + head];
            ACC2(q0, w0);
        }
    } else {
        float m[4], ssum[4];
        #pragma unroll
        for (int h = 0; h < 4; h++) { m[h] = -1e30f; ssum[h] = 0.f; }
        for (int base = start; base < end; base += 64) {
            int i = base + lane;
            bool valid = i < end;
            int idx = csr[valid ? i : start];
            float4 ev = *(const float4*)(es + (size_t)idx * 4);
            float e[4] = {ev.x, ev.y, ev.z, ev.w};
            #pragma unroll
            for (int h = 0; h < 4; h++) {
                float v = e[h] + edh[h];
                v = v > 0.f ? v : 0.2f * v;
                e[h] = valid ? v : -1e30f;
            }
            float cm[4];
            #pragma unroll
            for (int h = 0; h < 4; h++) cm[h] = e[h];
            #pragma unroll
            for (int o = 32; o >= 1; o >>= 1)
                #pragma unroll
                for (int h = 0; h < 4; h++) cm[h] = fmaxf(cm[h], __shfl_xor(cm[h], o, 64));
            float cs[4];
            #pragma unroll
            for (int h = 0; h < 4; h++) cs[h] = valid ? __expf(e[h] - cm[h]) : 0.f;
            #pragma unroll
            for (int o = 32; o >= 1; o >>= 1)
                #pragma unroll
                for (int h = 0; h < 4; h++) cs[h] += __shfl_xor(cs[h], o, 64);
            #pragma unroll
            for (int h = 0; h < 4; h++) {
                float mn = fmaxf(m[h], cm[h]);
                ssum[h] = ssum[h] * __expf(m[h] - mn) + cs[h] * __expf(cm[h] - mn);
                m[h] = mn;
            }
        }
        float inv[4];
        #pragma unroll
        for (int h = 0; h < 4; h++) inv[h] = 1.f / ssum[h];
        for (int base = start; base < end; base += 64) {
            int i = base + lane;
            bool valid = i < end;
            int idx = csr[valid ? i : start];
            int cnt = min(64, end - base);
            float4 ev = *(const float4*)(es + (size_t)idx * 4);
            float e[4] = {ev.x, ev.y, ev.z, ev.w};
            #pragma unroll
            for (int h = 0; h < 4; h++) {
                float v = e[h] + edh[h];
                v = v > 0.f ? v : 0.2f * v;
                e[h] = valid ? __expf(v - m[h]) * inv[h] : 0.f;
            }
            float4 wv; wv.x = e[0]; wv.y = e[1]; wv.z = e[2]; wv.w = e[3];
            *(float4*)&wlds[wave][lane * 4] = wv;
            for (int t = 0; t < cnt; ++t) {
                int s = __shfl(idx, t, 64);
                float w = wlds[wave][t * 4 + head];
                uint2 q = *(const uint2*)(xb + (size_t)s * 128 + lane * 2);
                ACC2(q, w);
            }
        }
    }

    float o0 = elu1(a0 + bias[lane * 4 + 0]);
    float o1 = elu1(a1 + bias[lane * 4 + 1]);
    float o2 = elu1(a2 + bias[lane * 4 + 2]);
    float o3 = elu1(a3 + bias[lane * 4 + 3]);
    if constexpr (BFOUT) {
        ushort4 o; o.x = f2bf(o0); o.y = f2bf(o1); o.z = f2bf(o2); o.w = f2bf(o3);
        *(ushort4*)((ushort_t*)outv + (size_t)node * 256 + lane * 4) = o;
    } else {
        float4 o; o.x = o0; o.y = o1; o.z = o2; o.w = o3;
        *(float4*)((float*)outv + (size_t)node * 256 + lane * 4) = o;
    }
}

// ------------------------------------------------- softmax aggregate, 1 head
// 4 nodes per wave (16-lane groups); partial mean-pool stored per block
// (no atomics — R4: 200k same-line atomics serialized at the coherent point).
__global__ __launch_bounds__(256) void k_agg1(const ushort_t* __restrict__ xl,
                                              const float* __restrict__ es,
                                              const float* __restrict__ ed,
                                              const int* __restrict__ row_ptr,
                                              const int* __restrict__ csr,
                                              const float* __restrict__ bias,
                                              float* __restrict__ part) {
    __shared__ float wlds[4][64];
    __shared__ float ps[4][64];
    int lane = threadIdx.x & 63, wave = threadIdx.x >> 6;
    int g = lane >> 4, l16 = lane & 15;
    int node = blockIdx.x * 16 + wave * 4 + g;
    bool vn = node < NN;
    int start = vn ? row_ptr[node] : 0;
    int end   = vn ? row_ptr[node + 1] : 0;
    float edl = vn ? ed[node] : 0.f;

    float m = -1e30f, ssum = 0.f;
    for (int base = start; base < end; base += 16) {
        int i = base + l16;
        bool valid = i < end;
        int idx = csr[valid ? i : start];
        float e = es[idx] + edl;
        e = e > 0.f ? e : 0.2f * e;
        e = valid ? e : -1e30f;
        float cm = e;
        #pragma unroll
        for (int o = 8; o >= 1; o >>= 1) cm = fmaxf(cm, __shfl_xor(cm, o, 64));
        float cs = valid ? __expf(e - cm) : 0.f;
        #pragma unroll
        for (int o = 8; o >= 1; o >>= 1) cs += __shfl_xor(cs, o, 64);
        float mn = fmaxf(m, cm);
        ssum = ssum * __expf(m - mn) + cs * __expf(cm - mn);
        m = mn;
    }
    float inv = 1.f / ssum;

    float a0 = 0.f, a1 = 0.f, a2 = 0.f, a3 = 0.f;
    const uint_t* xb = (const uint_t*)xl;
    for (int base = start; base < end; base += 16) {
        int i = base + l16;
        bool valid = i < end;
        int idx = csr[valid ? i : start];
        int cnt = min(16, end - base);
        float e = es[idx] + edl;
        e = e > 0.f ? e : 0.2f * e;
        wlds[wave][g * 16 + l16] = valid ? __expf(e - m) * inv : 0.f;
        int t = 0;
        for (; t + 4 <= cnt; t += 4) {
            int s0 = __shfl(idx, g * 16 + t + 0, 64), s1 = __shfl(idx, g * 16 + t + 1, 64);
            int s2 = __shfl(idx, g * 16 + t + 2, 64), s3 = __shfl(idx, g * 16 + t + 3, 64);
            uint2 q0 = *(const uint2*)(xb + (size_t)s0 * 32 + l16 * 2);
            uint2 q1 = *(const uint2*)(xb + (size_t)s1 * 32 + l16 * 2);
            uint2 q2 = *(const uint2*)(xb + (size_t)s2 * 32 + l16 * 2);
            uint2 q3 = *(const uint2*)(xb + (size_t)s3 * 32 + l16 * 2);
            float w0 = wlds[wave][g * 16 + t + 0], w1 = wlds[wave][g * 16 + t + 1];
            float w2 = wlds[wave][g * 16 + t + 2], w3 = wlds[wave][g * 16 + t + 3];
            ACC2(q0, w0); ACC2(q1, w1); ACC2(q2, w2); ACC2(q3, w3);
        }
        for (; t < cnt; ++t) {
            int s = __shfl(idx, g * 16 + t, 64);
            float w = wlds[wave][g * 16 + t];
            uint2 q = *(const uint2*)(xb + (size_t)s * 32 + l16 * 2);
            ACC2(q, w);
        }
    }

    float o[4];
    o[0] = vn ? elu1(a0 + bias[l16 * 4 + 0]) : 0.f;
    o[1] = vn ? elu1(a1 + bias[l16 * 4 + 1]) : 0.f;
    o[2] = vn ? elu1(a2 + bias[l16 * 4 + 2]) : 0.f;
    o[3] = vn ? elu1(a3 + bias[l16 * 4 + 3]) : 0.f;
    #pragma unroll
    for (int j = 0; j < 4; j++) {
        o[j] += __shfl_xor(o[j], 16, 64);
        o[j] += __shfl_xor(o[j], 32, 64);
    }
    if (lane < 16) {
        float4 v; v.x = o[0]; v.y = o[1]; v.z = o[2]; v.w = o[3];
        *(float4*)&ps[wave][l16 * 4] = v;
    }
    __syncthreads();
    int tid = threadIdx.x;
    if (tid < 64) {
        float tot = ps[0][tid] + ps[1][tid] + ps[2][tid] + ps[3][tid];
        part[(size_t)blockIdx.x * 64 + tid] = tot;
    }
}

// ---- reduce part[NAGG1][64] -> gsum[64] (few blocks => few atomics) ----
__global__ void k_red(const float* __restrict__ part, float* __restrict__ gsum) {
    __shared__ float sm[4][64];
    int t = threadIdx.x, c = t & 63, w = t >> 6;
    float s = 0.f;
    for (int r = blockIdx.x * 4 + w; r < NAGG1; r += gridDim.x * 4)
        s += part[(size_t)r * 64 + c];
    sm[w][c] = s;
    __syncthreads();
    if (w == 0) {
        float tot = sm[0][c] + sm[1][c] + sm[2][c] + sm[3][c];
        atomicAdd(&gsum[c], tot);
    }
}

// ---------------------------------------------------------------- final
__global__ void k_final(const float* __restrict__ gsum, const float* __restrict__ w_out,
                        const float* __restrict__ b_out, float* __restrict__ out) {
    int j = threadIdx.x;   // 128
    float s = b_out[j];
    const float invn = 1.f / (float)NN;
    #pragma unroll 8
    for (int k = 0; k < 64; k++)
        s += (gsum[k] * invn) * w_out[k * 128 + j];
    out[j] = s;
}

// ---------------------------------------------------------------- launcher
extern "C" void kernel_launch(void* const* d_in, const int* in_sizes, int n_in,
                              void* d_out, int out_size, void* d_ws, size_t ws_size,
                              hipStream_t stream) {
    const float* x    = (const float*)d_in[0];
    const int*   ei   = (const int*)d_in[1];
    const float* w_in = (const float*)d_in[2];
    const float* b_in = (const float*)d_in[3];
    const float* W0   = (const float*)d_in[4];
    const float* as0  = (const float*)d_in[5];
    const float* ad0  = (const float*)d_in[6];
    const float* bb0  = (const float*)d_in[7];
    const float* W1   = (const float*)d_in[8];
    const float* as1  = (const float*)d_in[9];
    const float* ad1  = (const float*)d_in[10];
    const float* bb1  = (const float*)d_in[11];
    const float* W2   = (const float*)d_in[12];
    const float* as2  = (const float*)d_in[13];
    const float* ad2  = (const float*)d_in[14];
    const float* bb2  = (const float*)d_in[15];
    const float* w_out= (const float*)d_in[16];
    const float* b_out= (const float*)d_in[17];
    float* out = (float*)d_out;

    char* p = (char*)d_ws;
    size_t off = 0;
    auto take = [&](size_t bytes) {
        char* r = p + off;
        off = (off + bytes + 255) & ~(size_t)255;
        return r;
    };
    ushort_t* h0b    = (ushort_t*)take((size_t)NN * 64 * 2);  //  6.4 MB
    ushort_t* xl_bf  = (ushort_t*)take((size_t)NN * 256 * 2); // 25.6 MB
    ushort_t* hb_bf  = (ushort_t*)take((size_t)NN * 256 * 2); // 25.6 MB
    ushort_t* h2_bf  = (ushort_t*)take((size_t)NN * 64 * 2);  //  6.4 MB
    ushort_t* wiT    = (ushort_t*)take((size_t)64 * 512 * 2);
    ushort_t* w0T    = (ushort_t*)take((size_t)256 * 128 * 2);
    ushort_t* w1T    = (ushort_t*)take((size_t)256 * 512 * 2);
    ushort_t* w2T    = (ushort_t*)take((size_t)64 * 512 * 2);
    float*    es     = (float*)take((size_t)NN * 4 * 4);
    float*    ed     = (float*)take((size_t)NN * 4 * 4);
    int*      row_ptr= (int*)take((size_t)(NN + 1) * 4);
    int*      cursor = (int*)take((size_t)NN * 4);
    int*      csr    = (int*)take((size_t)ET * 4);
    int*      bsum   = (int*)take((size_t)NBLK * 4);
    float*    part   = (float*)take((size_t)NAGG1 * 64 * 4);  // 0.8 MB
    float*    gsum   = (float*)take(64 * 4);

    // cursor := 0 (degree histogram base; self-loop +1 folded into scan1)
    hipMemsetAsync(cursor, 0, (size_t)NN * 4, stream);

    // ---- mega prep: weight split-transpose + dst histogram ----
    k_mega<<<MEGA_GRID, 256, 0, stream>>>(w_in, W0, W1, W2, wiT, w0T, w1T, w2T,
                                          ei + NE, cursor, gsum);

    // ---- scan (cnt+1) -> row_ptr ----
    k_scan1<<<NBLK, 256, 0, stream>>>(cursor, row_ptr, bsum);
    k_scan2<<<1, 256, 0, stream>>>(bsum);
    k_scan3<<<NBLK, 256, 0, stream>>>(row_ptr, bsum, cursor);

    // ---- fused A: input projection GEMM (fp32 A) || scatter [0,EHALF) ----
    k_fuseA<<<GM64 + SCA, 256, 0, stream>>>(x, wiT, b_in, h0b, ei, cursor, csr);

    // ---- fused B: GAT layer-0 GEMM (es/ed epilogue) || scatter [EHALF,ET) ----
    k_fuseB<<<2 * GM128 + SCB, 256, 0, stream>>>(h0b, w0T, xl_bf, as0, ad0,
                                                 es, ed, ei, cursor, csr);
    k_agg4<true><<<(NN + 3) / 4, 256, 0, stream>>>(xl_bf, es, ed, row_ptr, csr, bb0, hb_bf);

    // ---- GAT layer 1 (heads=4, concat); BN=128 ----
    gemm_mfma<false, false, true, 2, 8><<<dim3(GM128, 2), 256, 0, stream>>>(
        hb_bf, w1T, nullptr, xl_bf, as1, ad1, es, ed, 4, NN, 256, 256);
    k_agg4<true><<<(NN + 3) / 4, 256, 0, stream>>>(xl_bf, es, ed, row_ptr, csr, bb1, hb_bf);

    // ---- GAT layer 2 (heads=1) + partial mean-pool ----
    gemm_mfma<false, false, true, 1, 4><<<dim3(GM64, 1), 256, 0, stream>>>(
        hb_bf, w2T, nullptr, h2_bf, as2, ad2, es, ed, 1, NN, 256, 64);
    k_agg1<<<NAGG1, 256, 0, stream>>>(h2_bf, es, ed, row_ptr, csr, bb2, part);
    k_red <<<64, 256, 0, stream>>>(part, gsum);

    // ---- output projection ----
    k_final<<<1, 128, 0, stream>>>(gsum, w_out, b_out, out);
}

// Round 14
// 434.094 us; speedup vs baseline: 1.1467x; 1.0271x over previous
//
#include <hip/hip_runtime.h>

#define NN 50000
#define NE 800000
#define ET 850000   // NE + NN self-loops
#define NBLK 196    // ceil(NN/256) for the parallel scan
#define NAGG1 3125  // k_agg1 grid (= NN/16), also rows of `part`
#define MEGA_W    448                   // weight-prep blocks (114688/256)
#define MEGA_HIST 3125                  // hist blocks (NE/256)
#define MEGA_GRID (MEGA_W + MEGA_HIST)
#define GM64 782                        // (NN+63)/64
#define GM128 391                       // (NN+127)/128
#define EHALF 425000                    // scatter split point
#define SCA 1661                        // ceil(EHALF/256)
#define SCB 1661                        // ceil((ET-EHALF)/256)

typedef unsigned short ushort_t;
typedef unsigned int uint_t;
typedef __attribute__((ext_vector_type(8))) short short8;
typedef __attribute__((ext_vector_type(4))) float f32x4;

// ---------------------------------------------------------------- utilities
__device__ __forceinline__ float elu1(float x) {
    return x > 0.f ? x : (__expf(x) - 1.f);
}
__device__ __forceinline__ float bf2f(ushort_t u) {
    return __uint_as_float(((uint_t)u) << 16);
}
__device__ __forceinline__ ushort_t f2bf(float f) {   // round-to-nearest-even
    uint_t u = __float_as_uint(f);
    u += 0x7FFFu + ((u >> 16) & 1u);
    return (ushort_t)(u >> 16);
}
__device__ __forceinline__ uint_t pack2(float a, float b) {
    return (uint_t)f2bf(a) | ((uint_t)f2bf(b) << 16);
}
__device__ __forceinline__ void gl_lds16(const ushort_t* g, ushort_t* l) {
    // async global->LDS, 16B/lane; LDS dest = wave-uniform base + lane*16
    __builtin_amdgcn_global_load_lds((const __attribute__((address_space(1))) void*)g,
                                     (__attribute__((address_space(3))) void*)l,
                                     16, 0, 0);
}
// bf16 pair (packed in a dword) -> two fp32, exact (bf16 = truncated fp32)
#define ACC2(q, w) do { \
    a0 += (w) * __uint_as_float((q).x << 16); \
    a1 += (w) * __uint_as_float((q).x & 0xFFFF0000u); \
    a2 += (w) * __uint_as_float((q).y << 16); \
    a3 += (w) * __uint_as_float((q).y & 0xFFFF0000u); } while (0)

// ---------------------------------------------------------------- mega prep
// blocks [0,448): weight split-transposes with column permutation:
//   within each 64-col group, col j -> row (j&3)*16 + (j>>2): GEMM frag nt
//   slot l16 = global col l16*4+nt -> lanes own 4 consecutive output cols.
// blocks [448,3573): dst-degree histogram (cursor pre-zeroed by memset;
//   the +1 self-loop is folded into k_scan1).
// NOTE R12: radix-bucketed scatter REGRESSED (443->498): bucket cursors
//   shared across concurrent waves interleave partial-line writes (same 16x
//   write amp) + 850k atomics on only 196 lines serialize. Flat scatter
//   hidden under GEMMs (this version) is the best known.
__global__ void k_mega(const float* __restrict__ w_in, const float* __restrict__ W0,
                       const float* __restrict__ W1, const float* __restrict__ W2,
                       ushort_t* __restrict__ wiT, ushort_t* __restrict__ w0T,
                       ushort_t* __restrict__ w1T, ushort_t* __restrict__ w2T,
                       const int* __restrict__ dst, int* __restrict__ cursor,
                       float* __restrict__ gsum, int* __restrict__ tcount) {
    int b = blockIdx.x, t = threadIdx.x;
    if (b < MEGA_W) {
        if (b == 0 && t < 64) gsum[t] = 0.f;
        if (b == 0 && t == 64) *tcount = 0;
        int i = b * 256 + t;                      // 0..114687
        const float* W; ushort_t* Bt; int K, N, j;
        if (i < 16384)       { W = w_in; Bt = wiT; K = 256; N = 64;  j = i; }
        else if (i < 32768)  { W = W0;   Bt = w0T; K = 64;  N = 256; j = i - 16384; }
        else if (i < 98304)  { W = W1;   Bt = w1T; K = 256; N = 256; j = i - 32768; }
        else                 { W = W2;   Bt = w2T; K = 256; N = 64;  j = i - 98304; }
        int k = j / N, n = j % N;
        int jj = n & 63;
        int rp = (n & ~63) | ((jj & 3) << 4) | (jj >> 2);   // permuted row
        float v = W[j];
        ushort_t h = f2bf(v);
        Bt[(size_t)rp * 2 * K + k] = h;
        Bt[(size_t)rp * 2 * K + K + k] = f2bf(v - bf2f(h));
    } else {
        int e = (b - MEGA_W) * 256 + t;
        if (e < NE) atomicAdd(&cursor[dst[e]], 1);
    }
}

// ---------------------------------------------------------------- scan
// exclusive scan of (cnt[i]+1) -> row_ptr (the +1 is the self-loop)
__global__ void k_scan1(const int* __restrict__ cnt, int* __restrict__ excl,
                        int* __restrict__ bsum) {
    __shared__ int wsum[4];
    int t = threadIdx.x, lane = t & 63, w = t >> 6;
    int i = blockIdx.x * 256 + t;
    int v = (i < NN) ? cnt[i] + 1 : 0;
    int x = v;
    #pragma unroll
    for (int o = 1; o < 64; o <<= 1) {
        int y = __shfl_up(x, o, 64);
        if (lane >= o) x += y;
    }
    if (lane == 63) wsum[w] = x;
    __syncthreads();
    int wo = 0;
    #pragma unroll
    for (int k = 0; k < 4; k++) wo += (k < w) ? wsum[k] : 0;
    if (i < NN) excl[i] = x - v + wo;
    if (t == 255) bsum[blockIdx.x] = wo + x;     // block total
}

// scan3 with scan2 folded in: each block computes its own prefix over the
// 196 block totals (L2-hot; removes the serialized 1-block scan2 launch).
__global__ void k_scan3(int* __restrict__ row_ptr, const int* __restrict__ bsum,
                        int* __restrict__ cursor) {
    __shared__ int red[4];
    int t = threadIdx.x, lane = t & 63, w = t >> 6;
    int partial = 0;
    for (int k = t; k < blockIdx.x; k += 256) partial += bsum[k];
    #pragma unroll
    for (int o = 32; o >= 1; o >>= 1) partial += __shfl_xor(partial, o, 64);
    if (lane == 0) red[w] = partial;
    __syncthreads();
    int off = red[0] + red[1] + red[2] + red[3];
    int i = blockIdx.x * 256 + t;
    if (i < NN) {
        int r = row_ptr[i] + off;
        row_ptr[i] = r;
        cursor[i] = r;
    }
    if (i == 0) row_ptr[NN] = ET;
}

// ---------------------------------------------------------------- GEMM body
// C[M x N](bf16) = A[M x K] @ (Bh + Bl), split-bf16 weights.
// AF32: A is fp32; staging converts RNE in-register + ds_write_b128 (bit-
// identical to a separate cast pass). Else A is bf16 via global_load_lds.
// BM=64*MT, BN=16*NT (NT=8 for N=256 GEMMs -> halves A refetch). 256 thr.
// Weight cols permuted (see k_mega) -> ushort4 C stores, float4 bias loads.
template<bool ELU, bool BIAS, bool EDOT, int MT, int NT, bool AF32>
__device__ __forceinline__ void gemm_body(const void* __restrict__ Av,
                                          const ushort_t* __restrict__ Bt,
                                          const float* __restrict__ bias,
                                          ushort_t* __restrict__ C,
                                          const float* __restrict__ a_s,
                                          const float* __restrict__ a_d,
                                          float* __restrict__ es,
                                          float* __restrict__ ed,
                                          int esStride, int M, int K, int N,
                                          int bx, int by) {
    constexpr int HG = NT / 4;                    // 64-col groups per block
    constexpr int BOFF = MT * 4096;               // ushort offset of B region
    __shared__ __align__(16) ushort_t lds[MT * 4096 + NT * 2048];
    int tid = threadIdx.x;
    int wave = tid >> 6, lane = tid & 63;
    int quad = lane >> 4, l16 = lane & 15;
    int mb = bx * (64 * MT), nb = by * (16 * NT);
    int K2 = 2 * K;

    f32x4 acc[MT][NT];
    #pragma unroll
    for (int mt = 0; mt < MT; mt++)
        #pragma unroll
        for (int nt = 0; nt < NT; nt++)
            acc[mt][nt] = (f32x4){0.f, 0.f, 0.f, 0.f};

    for (int k0 = 0; k0 < K; k0 += 64) {
        // ---- stage B first (async DMA) ----
        #pragma unroll
        for (int c = 0; c < NT; c++) {
            int id = wave * NT + c;               // 0 .. 4*NT-1
            int ntile = id % NT;
            int ks = (id / NT) & 1;
            int split = id / (2 * NT);
            int n = nb + ntile * 16 + l16;
            int col = split * K + k0 + ks * 32 + quad * 8;
            gl_lds16(Bt + (size_t)n * K2 + col,
                     &lds[BOFF + ((split * NT + ntile) * 2 + ks) * 512]);
        }
        // ---- stage A ----
        #pragma unroll
        for (int c = 0; c < 2 * MT; c++) {
            int mt = (MT == 2) ? (wave * 2 + (c >> 1)) : wave;
            int ks = (MT == 2) ? (c & 1) : c;
            int row = mb + mt * 16 + l16;
            row = min(row, M - 1);
            int col = k0 + ks * 32 + quad * 8;
            if constexpr (AF32) {
                const float* Af = (const float*)Av;
                float4 v0 = *(const float4*)(Af + (size_t)row * K + col);
                float4 v1 = *(const float4*)(Af + (size_t)row * K + col + 4);
                uint4 pk;
                pk.x = pack2(v0.x, v0.y); pk.y = pack2(v0.z, v0.w);
                pk.z = pack2(v1.x, v1.y); pk.w = pack2(v1.z, v1.w);
                *(uint4*)&lds[(mt * 2 + ks) * 512 + lane * 8] = pk;
            } else {
                gl_lds16((const ushort_t*)Av + (size_t)row * K + col,
                         &lds[(mt * 2 + ks) * 512]);
            }
        }
        __syncthreads();
        #pragma unroll
        for (int ks = 0; ks < 2; ks++) {
            short8 af[MT];
            #pragma unroll
            for (int mt = 0; mt < MT; mt++)
                af[mt] = *(const short8*)&lds[((wave * MT + mt) * 2 + ks) * 512 + lane * 8];
            #pragma unroll
            for (int split = 0; split < 2; split++) {
                short8 bf[NT];
                #pragma unroll
                for (int nt = 0; nt < NT; nt++)
                    bf[nt] = *(const short8*)&lds[BOFF + ((split * NT + nt) * 2 + ks) * 512 + lane * 8];
                #pragma unroll
                for (int mt = 0; mt < MT; mt++)
                    #pragma unroll
                    for (int nt = 0; nt < NT; nt++)
                        acc[mt][nt] = __builtin_amdgcn_mfma_f32_16x16x32_bf16(
                            af[mt], bf[nt], acc[mt][nt], 0, 0, 0);
            }
        }
        __syncthreads();
    }
    // ---- epilogue: frag nt slot l16 = global col l16*4 + (nt%4), group nt/4 ----
    float4 as4[HG], ad4[HG], b4[HG];
    #pragma unroll
    for (int hg = 0; hg < HG; hg++) {
        int cbase = nb + hg * 64 + l16 * 4;
        if (EDOT) {
            as4[hg] = *(const float4*)(a_s + (size_t)(by * HG + hg) * 64 + l16 * 4);
            ad4[hg] = *(const float4*)(a_d + (size_t)(by * HG + hg) * 64 + l16 * 4);
        }
        if (BIAS) b4[hg] = *(const float4*)(bias + cbase);
    }
    #pragma unroll
    for (int mt = 0; mt < MT; mt++) {
        int mrow = mb + (wave * MT + mt) * 16 + quad * 4;
        #pragma unroll
        for (int r = 0; r < 4; r++) {
            int m = mrow + r;
            bool mv = m < M;
            #pragma unroll
            for (int hg = 0; hg < HG; hg++) {
                float v0 = acc[mt][hg * 4 + 0][r];
                float v1 = acc[mt][hg * 4 + 1][r];
                float v2 = acc[mt][hg * 4 + 2][r];
                float v3 = acc[mt][hg * 4 + 3][r];
                if constexpr (EDOT) {
                    float ps = v0 * as4[hg].x + v1 * as4[hg].y + v2 * as4[hg].z + v3 * as4[hg].w;
                    float pd = v0 * ad4[hg].x + v1 * ad4[hg].y + v2 * ad4[hg].z + v3 * ad4[hg].w;
                    #pragma unroll
                    for (int o = 8; o >= 1; o >>= 1) {
                        ps += __shfl_xor(ps, o, 64);
                        pd += __shfl_xor(pd, o, 64);
                    }
                    if (l16 == 0 && mv) {
                        int head = by * HG + hg;
                        es[(size_t)m * esStride + head] = ps;
                        ed[(size_t)m * esStride + head] = pd;
                    }
                }
                if (mv) {
                    if (BIAS) { v0 += b4[hg].x; v1 += b4[hg].y; v2 += b4[hg].z; v3 += b4[hg].w; }
                    if (ELU) { v0 = elu1(v0); v1 = elu1(v1); v2 = elu1(v2); v3 = elu1(v3); }
                    ushort4 o;
                    o.x = f2bf(v0); o.y = f2bf(v1); o.z = f2bf(v2); o.w = f2bf(v3);
                    *(ushort4*)&C[(size_t)m * N + nb + hg * 64 + l16 * 4] = o;
                }
            }
        }
    }
}

template<bool ELU, bool BIAS, bool EDOT, int MT, int NT>
__global__ __launch_bounds__(256) void gemm_mfma(const ushort_t* __restrict__ A,
                                                 const ushort_t* __restrict__ Bt,
                                                 const float* __restrict__ bias,
                                                 ushort_t* __restrict__ C,
                                                 const float* __restrict__ a_s,
                                                 const float* __restrict__ a_d,
                                                 float* __restrict__ es,
                                                 float* __restrict__ ed,
                                                 int esStride, int M, int K, int N) {
    gemm_body<ELU, BIAS, EDOT, MT, NT, false>(A, Bt, bias, C, a_s, a_d, es, ed,
                                              esStride, M, K, N, blockIdx.x, blockIdx.y);
}

// ---- fused launch A: input-projection GEMM reading fp32 x directly
//      (blocks [0,GM64)) + CSR scatter of edges [0,EHALF).
__global__ __launch_bounds__(256) void k_fuseA(const float* __restrict__ x,
                                               const ushort_t* __restrict__ Bt,
                                               const float* __restrict__ bias,
                                               ushort_t* __restrict__ C,
                                               const int* __restrict__ ei,
                                               int* __restrict__ cursor,
                                               int* __restrict__ csr) {
    if (blockIdx.x < GM64) {
        gemm_body<true, true, false, 1, 4, true>(x, Bt, bias, C, nullptr, nullptr,
                                                 nullptr, nullptr, 0, NN, 256, 64,
                                                 blockIdx.x, 0);
    } else {
        int e = (blockIdx.x - GM64) * 256 + threadIdx.x;
        if (e >= EHALF) return;               // EHALF < NE: all real edges
        int s = ei[e], d = ei[NE + e];
        int pos = atomicAdd(&cursor[d], 1);
        csr[pos] = s;
    }
}

// ---- fused launch B: GAT-layer-0 GEMM (flattened 391x2 grid, blocks
//      [0,782)) + CSR scatter of edges [EHALF,ET) incl. self-loops.
__global__ __launch_bounds__(256) void k_fuseB(const ushort_t* __restrict__ A,
                                               const ushort_t* __restrict__ Bt,
                                               ushort_t* __restrict__ C,
                                               const float* __restrict__ a_s,
                                               const float* __restrict__ a_d,
                                               float* __restrict__ es,
                                               float* __restrict__ ed,
                                               const int* __restrict__ ei,
                                               int* __restrict__ cursor,
                                               int* __restrict__ csr) {
    if (blockIdx.x < 2 * GM128) {
        int g = blockIdx.x;
        gemm_body<false, false, true, 2, 8, false>(A, Bt, nullptr, C, a_s, a_d, es, ed,
                                                   4, NN, 64, 256, g % GM128, g / GM128);
    } else {
        int e = EHALF + (blockIdx.x - 2 * GM128) * 256 + threadIdx.x;
        if (e >= ET) return;
        int s, d;
        if (e < NE) { s = ei[e]; d = ei[NE + e]; }
        else        { s = d = e - NE; }
        int pos = atomicAdd(&cursor[d], 1);
        csr[pos] = s;
    }
}

// ------------------------------------------------- softmax aggregate, 4 heads
// 1 wave per node; fast path deg<=64; gather unrolled x4 (R7: x8 regressed via
// VGPR 24->36). At fabric floor: 207 MB compulsory 8-XCD gather traffic @
// ~3.6 TB/s observed ceiling (stable across 6 configurations R1..R13).
template<bool BFOUT>
__global__ __launch_bounds__(256) void k_agg4(const ushort_t* __restrict__ xl,
                                              const float* __restrict__ es,
                                              const float* __restrict__ ed,
                                              const int* __restrict__ row_ptr,
                                              const int* __restrict__ csr,
                                              const float* __restrict__ bias,
                                              void* __restrict__ outv) {
    __shared__ float wlds[4][256];
    int lane = threadIdx.x & 63, wave = threadIdx.x >> 6;
    int node = blockIdx.x * 4 + wave;
    if (node >= NN) return;
    int head = lane >> 4;
    int start = row_ptr[node], end = row_ptr[node + 1];
    int deg = end - start;
    float4 edv = *(const float4*)(ed + (size_t)node * 4);
    float edh[4] = {edv.x, edv.y, edv.z, edv.w};
    float a0 = 0.f, a1 = 0.f, a2 = 0.f, a3 = 0.f;
    const uint_t* xb = (const uint_t*)xl;

    if (deg <= 64) {
        int i = start + lane;
        bool valid = i < end;
        int idx = csr[valid ? i : start];
        float4 ev = *(const float4*)(es + (size_t)idx * 4);
        float e[4] = {ev.x, ev.y, ev.z, ev.w};
        #pragma unroll
        for (int h = 0; h < 4; h++) {
            float v = e[h] + edh[h];
            v = v > 0.f ? v : 0.2f * v;
            e[h] = valid ? v : -1e30f;
        }
        float cm[4];
        #pragma unroll
        for (int h = 0; h < 4; h++) cm[h] = e[h];
        #pragma unroll
        for (int o = 32; o >= 1; o >>= 1)
            #pragma unroll
            for (int h = 0; h < 4; h++) cm[h] = fmaxf(cm[h], __shfl_xor(cm[h], o, 64));
        float cs[4];
        #pragma unroll
        for (int h = 0; h < 4; h++) cs[h] = valid ? __expf(e[h] - cm[h]) : 0.f;
        #pragma unroll
        for (int o = 32; o >= 1; o >>= 1)
            #pragma unroll
            for (int h = 0; h < 4; h++) cs[h] += __shfl_xor(cs[h], o, 64);
        float4 wv;
        wv.x = valid ? __expf(e[0] - cm[0]) / cs[0] : 0.f;
        wv.y = valid ? __expf(e[1] - cm[1]) / cs[1] : 0.f;
        wv.z = valid ? __expf(e[2] - cm[2]) / cs[2] : 0.f;
        wv.w = valid ? __expf(e[3] - cm[3]) / cs[3] : 0.f;
        *(float4*)&wlds[wave][lane * 4] = wv;
        int t = 0;
        for (; t + 4 <= deg; t += 4) {
            int s0 = __shfl(idx, t + 0, 64), s1 = __shfl(idx, t + 1, 64);
            int s2 = __shfl(idx, t + 2, 64), s3 = __shfl(idx, t + 3, 64);
            uint2 q0 = *(const uint2*)(xb + (size_t)s0 * 128 + lane * 2);
            uint2 q1 = *(const uint2*)(xb + (size_t)s1 * 128 + lane * 2);
            uint2 q2 = *(const uint2*)(xb + (size_t)s2 * 128 + lane * 2);
            uint2 q3 = *(const uint2*)(xb + (size_t)s3 * 128 + lane * 2);
            float w0 = wlds[wave][(t + 0) * 4 + head], w1 = wlds[wave][(t + 1) * 4 + head];
            float w2 = wlds[wave][(t + 2) * 4 + head], w3 = wlds[wave][(t + 3) * 4 + head];
            ACC2(q0, w0); ACC2(q1, w1); ACC2(q2, w2); ACC2(q3, w3);
        }
        for (; t < deg; ++t) {
            int s0 = __shfl(idx, t, 64);
            uint2 q0 = *(const uint2*)(xb + (size_t)s0 * 128 + lane * 2);
            float w0 = wlds[wave][t * 4 + head];
            ACC2(q0, w0);
        }
    } else {
        float m[4], ssum[4];
        #pragma unroll
        for (int h = 0; h < 4; h++) { m[h] = -1e30f; ssum[h] = 0.f; }
        for (int base = start; base < end; base += 64) {
            int i = base + lane;
            bool valid = i < end;
            int idx = csr[valid ? i : start];
            float4 ev = *(const float4*)(es + (size_t)idx * 4);
            float e[4] = {ev.x, ev.y, ev.z, ev.w};
            #pragma unroll
            for (int h = 0; h < 4; h++) {
                float v = e[h] + edh[h];
                v = v > 0.f ? v : 0.2f * v;
                e[h] = valid ? v : -1e30f;
            }
            float cm[4];
            #pragma unroll
            for (int h = 0; h < 4; h++) cm[h] = e[h];
            #pragma unroll
            for (int o = 32; o >= 1; o >>= 1)
                #pragma unroll
                for (int h = 0; h < 4; h++) cm[h] = fmaxf(cm[h], __shfl_xor(cm[h], o, 64));
            float cs[4];
            #pragma unroll
            for (int h = 0; h < 4; h++) cs[h] = valid ? __expf(e[h] - cm[h]) : 0.f;
            #pragma unroll
            for (int o = 32; o >= 1; o >>= 1)
                #pragma unroll
                for (int h = 0; h < 4; h++) cs[h] += __shfl_xor(cs[h], o, 64);
            #pragma unroll
            for (int h = 0; h < 4; h++) {
                float mn = fmaxf(m[h], cm[h]);
                ssum[h] = ssum[h] * __expf(m[h] - mn) + cs[h] * __expf(cm[h] - mn);
                m[h] = mn;
            }
        }
        float inv[4];
        #pragma unroll
        for (int h = 0; h < 4; h++) inv[h] = 1.f / ssum[h];
        for (int base = start; base < end; base += 64) {
            int i = base + lane;
            bool valid = i < end;
            int idx = csr[valid ? i : start];
            int cnt = min(64, end - base);
            float4 ev = *(const float4*)(es + (size_t)idx * 4);
            float e[4] = {ev.x, ev.y, ev.z, ev.w};
            #pragma unroll
            for (int h = 0; h < 4; h++) {
                float v = e[h] + edh[h];
                v = v > 0.f ? v : 0.2f * v;
                e[h] = valid ? __expf(v - m[h]) * inv[h] : 0.f;
            }
            float4 wv; wv.x = e[0]; wv.y = e[1]; wv.z = e[2]; wv.w = e[3];
            *(float4*)&wlds[wave][lane * 4] = wv;
            for (int t = 0; t < cnt; ++t) {
                int s = __shfl(idx, t, 64);
                float w = wlds[wave][t * 4 + head];
                uint2 q = *(const uint2*)(xb + (size_t)s * 128 + lane * 2);
                ACC2(q, w);
            }
        }
    }

    float o0 = elu1(a0 + bias[lane * 4 + 0]);
    float o1 = elu1(a1 + bias[lane * 4 + 1]);
    float o2 = elu1(a2 + bias[lane * 4 + 2]);
    float o3 = elu1(a3 + bias[lane * 4 + 3]);
    if constexpr (BFOUT) {
        ushort4 o; o.x = f2bf(o0); o.y = f2bf(o1); o.z = f2bf(o2); o.w = f2bf(o3);
        *(ushort4*)((ushort_t*)outv + (size_t)node * 256 + lane * 4) = o;
    } else {
        float4 o; o.x = o0; o.y = o1; o.z = o2; o.w = o3;
        *(float4*)((float*)outv + (size_t)node * 256 + lane * 4) = o;
    }
}

// ------------------------------------------------- softmax aggregate, 1 head
// 4 nodes per wave (16-lane groups); partial mean-pool stored per block
// (no atomics — R4: 200k same-line atomics serialized at the coherent point).
__global__ __launch_bounds__(256) void k_agg1(const ushort_t* __restrict__ xl,
                                              const float* __restrict__ es,
                                              const float* __restrict__ ed,
                                              const int* __restrict__ row_ptr,
                                              const int* __restrict__ csr,
                                              const float* __restrict__ bias,
                                              float* __restrict__ part) {
    __shared__ float wlds[4][64];
    __shared__ float ps[4][64];
    int lane = threadIdx.x & 63, wave = threadIdx.x >> 6;
    int g = lane >> 4, l16 = lane & 15;
    int node = blockIdx.x * 16 + wave * 4 + g;
    bool vn = node < NN;
    int start = vn ? row_ptr[node] : 0;
    int end   = vn ? row_ptr[node + 1] : 0;
    float edl = vn ? ed[node] : 0.f;

    float m = -1e30f, ssum = 0.f;
    for (int base = start; base < end; base += 16) {
        int i = base + l16;
        bool valid = i < end;
        int idx = csr[valid ? i : start];
        float e = es[idx] + edl;
        e = e > 0.f ? e : 0.2f * e;
        e = valid ? e : -1e30f;
        float cm = e;
        #pragma unroll
        for (int o = 8; o >= 1; o >>= 1) cm = fmaxf(cm, __shfl_xor(cm, o, 64));
        float cs = valid ? __expf(e - cm) : 0.f;
        #pragma unroll
        for (int o = 8; o >= 1; o >>= 1) cs += __shfl_xor(cs, o, 64);
        float mn = fmaxf(m, cm);
        ssum = ssum * __expf(m - mn) + cs * __expf(cm - mn);
        m = mn;
    }
    float inv = 1.f / ssum;

    float a0 = 0.f, a1 = 0.f, a2 = 0.f, a3 = 0.f;
    const uint_t* xb = (const uint_t*)xl;
    for (int base = start; base < end; base += 16) {
        int i = base + l16;
        bool valid = i < end;
        int idx = csr[valid ? i : start];
        int cnt = min(16, end - base);
        float e = es[idx] + edl;
        e = e > 0.f ? e : 0.2f * e;
        wlds[wave][g * 16 + l16] = valid ? __expf(e - m) * inv : 0.f;
        int t = 0;
        for (; t + 4 <= cnt; t += 4) {
            int s0 = __shfl(idx, g * 16 + t + 0, 64), s1 = __shfl(idx, g * 16 + t + 1, 64);
            int s2 = __shfl(idx, g * 16 + t + 2, 64), s3 = __shfl(idx, g * 16 + t + 3, 64);
            uint2 q0 = *(const uint2*)(xb + (size_t)s0 * 32 + l16 * 2);
            uint2 q1 = *(const uint2*)(xb + (size_t)s1 * 32 + l16 * 2);
            uint2 q2 = *(const uint2*)(xb + (size_t)s2 * 32 + l16 * 2);
            uint2 q3 = *(const uint2*)(xb + (size_t)s3 * 32 + l16 * 2);
            float w0 = wlds[wave][g * 16 + t + 0], w1 = wlds[wave][g * 16 + t + 1];
            float w2 = wlds[wave][g * 16 + t + 2], w3 = wlds[wave][g * 16 + t + 3];
            ACC2(q0, w0); ACC2(q1, w1); ACC2(q2, w2); ACC2(q3, w3);
        }
        for (; t < cnt; ++t) {
            int s = __shfl(idx, g * 16 + t, 64);
            float w = wlds[wave][g * 16 + t];
            uint2 q = *(const uint2*)(xb + (size_t)s * 32 + l16 * 2);
            ACC2(q, w);
        }
    }

    float o[4];
    o[0] = vn ? elu1(a0 + bias[l16 * 4 + 0]) : 0.f;
    o[1] = vn ? elu1(a1 + bias[l16 * 4 + 1]) : 0.f;
    o[2] = vn ? elu1(a2 + bias[l16 * 4 + 2]) : 0.f;
    o[3] = vn ? elu1(a3 + bias[l16 * 4 + 3]) : 0.f;
    #pragma unroll
    for (int j = 0; j < 4; j++) {
        o[j] += __shfl_xor(o[j], 16, 64);
        o[j] += __shfl_xor(o[j], 32, 64);
    }
    if (lane < 16) {
        float4 v; v.x = o[0]; v.y = o[1]; v.z = o[2]; v.w = o[3];
        *(float4*)&ps[wave][l16 * 4] = v;
    }
    __syncthreads();
    int tid = threadIdx.x;
    if (tid < 64) {
        float tot = ps[0][tid] + ps[1][tid] + ps[2][tid] + ps[3][tid];
        part[(size_t)blockIdx.x * 64 + tid] = tot;
    }
}

// ---- reduce part[NAGG1][64] -> gsum[64]; LAST block (ticket) also does the
//      final 64x128 output GEMV (k_final fused; intra-kernel visibility via
//      threadfence + device-scope atomic loads — G16).
__global__ void k_red(const float* __restrict__ part, float* __restrict__ gsum,
                      int* __restrict__ tcount, const float* __restrict__ w_out,
                      const float* __restrict__ b_out, float* __restrict__ out) {
    __shared__ float sm[4][64];
    __shared__ float gs[64];
    __shared__ int lastFlag;
    int t = threadIdx.x, c = t & 63, w = t >> 6;
    float s = 0.f;
    for (int r = blockIdx.x * 4 + w; r < NAGG1; r += gridDim.x * 4)
        s += part[(size_t)r * 64 + c];
    sm[w][c] = s;
    __syncthreads();
    if (w == 0) {
        float tot = sm[0][c] + sm[1][c] + sm[2][c] + sm[3][c];
        atomicAdd(&gsum[c], tot);
    }
    if (t == 0) {
        __threadfence();                       // drain this wave's gsum atomics
        lastFlag = (atomicAdd(tcount, 1) == 63);
    }
    __syncthreads();
    if (!lastFlag) return;
    // last block: all 64 blocks' gsum atomics complete; read coherently
    if (t < 64)
        gs[t] = __hip_atomic_load(&gsum[t], __ATOMIC_ACQUIRE, __HIP_MEMORY_SCOPE_AGENT);
    __syncthreads();
    if (t < 128) {
        float acc = b_out[t];
        const float invn = 1.f / (float)NN;
        #pragma unroll 8
        for (int k = 0; k < 64; k++)
            acc += (gs[k] * invn) * w_out[k * 128 + t];
        out[t] = acc;
    }
}

// ---------------------------------------------------------------- launcher
extern "C" void kernel_launch(void* const* d_in, const int* in_sizes, int n_in,
                              void* d_out, int out_size, void* d_ws, size_t ws_size,
                              hipStream_t stream) {
    const float* x    = (const float*)d_in[0];
    const int*   ei   = (const int*)d_in[1];
    const float* w_in = (const float*)d_in[2];
    const float* b_in = (const float*)d_in[3];
    const float* W0   = (const float*)d_in[4];
    const float* as0  = (const float*)d_in[5];
    const float* ad0  = (const float*)d_in[6];
    const float* bb0  = (const float*)d_in[7];
    const float* W1   = (const float*)d_in[8];
    const float* as1  = (const float*)d_in[9];
    const float* ad1  = (const float*)d_in[10];
    const float* bb1  = (const float*)d_in[11];
    const float* W2   = (const float*)d_in[12];
    const float* as2  = (const float*)d_in[13];
    const float* ad2  = (const float*)d_in[14];
    const float* bb2  = (const float*)d_in[15];
    const float* w_out= (const float*)d_in[16];
    const float* b_out= (const float*)d_in[17];
    float* out = (float*)d_out;

    char* p = (char*)d_ws;
    size_t off = 0;
    auto take = [&](size_t bytes) {
        char* r = p + off;
        off = (off + bytes + 255) & ~(size_t)255;
        return r;
    };
    ushort_t* h0b    = (ushort_t*)take((size_t)NN * 64 * 2);  //  6.4 MB
    ushort_t* xl_bf  = (ushort_t*)take((size_t)NN * 256 * 2); // 25.6 MB
    ushort_t* hb_bf  = (ushort_t*)take((size_t)NN * 256 * 2); // 25.6 MB
    ushort_t* h2_bf  = (ushort_t*)take((size_t)NN * 64 * 2);  //  6.4 MB
    ushort_t* wiT    = (ushort_t*)take((size_t)64 * 512 * 2);
    ushort_t* w0T    = (ushort_t*)take((size_t)256 * 128 * 2);
    ushort_t* w1T    = (ushort_t*)take((size_t)256 * 512 * 2);
    ushort_t* w2T    = (ushort_t*)take((size_t)64 * 512 * 2);
    float*    es     = (float*)take((size_t)NN * 4 * 4);
    float*    ed     = (float*)take((size_t)NN * 4 * 4);
    int*      row_ptr= (int*)take((size_t)(NN + 1) * 4);
    int*      cursor = (int*)take((size_t)NN * 4);
    int*      csr    = (int*)take((size_t)ET * 4);
    int*      bsum   = (int*)take((size_t)NBLK * 4);
    float*    part   = (float*)take((size_t)NAGG1 * 64 * 4);  // 0.8 MB
    float*    gsum   = (float*)take(64 * 4);
    int*      tcount = (int*)take(4);

    // cursor := 0 (degree histogram base; self-loop +1 folded into scan1)
    hipMemsetAsync(cursor, 0, (size_t)NN * 4, stream);

    // ---- mega prep: weight split-transpose + dst histogram ----
    k_mega<<<MEGA_GRID, 256, 0, stream>>>(w_in, W0, W1, W2, wiT, w0T, w1T, w2T,
                                          ei + NE, cursor, gsum, tcount);

    // ---- scan (cnt+1) -> row_ptr (scan2 folded into scan3) ----
    k_scan1<<<NBLK, 256, 0, stream>>>(cursor, row_ptr, bsum);
    k_scan3<<<NBLK, 256, 0, stream>>>(row_ptr, bsum, cursor);

    // ---- fused A: input projection GEMM (fp32 A) || scatter [0,EHALF) ----
    k_fuseA<<<GM64 + SCA, 256, 0, stream>>>(x, wiT, b_in, h0b, ei, cursor, csr);

    // ---- fused B: GAT layer-0 GEMM (es/ed epilogue) || scatter [EHALF,ET) ----
    k_fuseB<<<2 * GM128 + SCB, 256, 0, stream>>>(h0b, w0T, xl_bf, as0, ad0,
                                                 es, ed, ei, cursor, csr);
    k_agg4<true><<<(NN + 3) / 4, 256, 0, stream>>>(xl_bf, es, ed, row_ptr, csr, bb0, hb_bf);

    // ---- GAT layer 1 (heads=4, concat); BN=128 ----
    gemm_mfma<false, false, true, 2, 8><<<dim3(GM128, 2), 256, 0, stream>>>(
        hb_bf, w1T, nullptr, xl_bf, as1, ad1, es, ed, 4, NN, 256, 256);
    k_agg4<true><<<(NN + 3) / 4, 256, 0, stream>>>(xl_bf, es, ed, row_ptr, csr, bb1, hb_bf);

    // ---- GAT layer 2 (heads=1) + partial mean-pool ----
    gemm_mfma<false, false, true, 1, 4><<<dim3(GM64, 1), 256, 0, stream>>>(
        hb_bf, w2T, nullptr, h2_bf, as2, ad2, es, ed, 1, NN, 256, 64);
    k_agg1<<<NAGG1, 256, 0, stream>>>(h2_bf, es, ed, row_ptr, csr, bb2, part);

    // ---- reduce + fused output projection (last-block ticket) ----
    k_red<<<64, 256, 0, stream>>>(part, gsum, tcount, w_out, b_out, out);
}